// Round 12
// baseline (295.737 us; speedup 1.0000x reference)
//
#include <hip/hip_runtime.h>
#include <hip/hip_bf16.h>
#include <math.h>

// Problem constants
#define NB   2
#define CIN  256
#define CC   512
#define GG   8
#define CGR  64
#define HH   48
#define WW   48
#define PP   (HH*WW)        // 2304
#define HD   46
#define WD   46
#define DD   (HD*WD)        // 2116
#define VSTRIDE 135680      // per-ng V size: 66 chunks*2048 + 512 tail (= old 64*2120)
#define VTAIL  135168       // compact tail offset (keys 2112..2115, co*8 + dk, upper 4 zeroed)
#define WRT  589824         // 512*9*128 = 8*36*2048, per-tensor reordered weight stride

typedef __bf16 bf16x8 __attribute__((ext_vector_type(8)));
typedef float  f32x4  __attribute__((ext_vector_type(4)));

__device__ __forceinline__ bf16x8 ldb8(const __hip_bfloat16* p) {
    return *reinterpret_cast<const bf16x8*>(p);
}
__device__ __forceinline__ void store4bf(__hip_bfloat16* p, f32x4 v) {
    union { __hip_bfloat16 h[4]; uint2 u; } t;
    #pragma unroll
    for (int r = 0; r < 4; ++r) t.h[r] = (__hip_bfloat16)v[r];
    *reinterpret_cast<uint2*>(p) = t.u;
}
__device__ __forceinline__ float ex2(float x) {
    return __builtin_amdgcn_exp2f(x);
}
// sigmoid(x) = 1/(1+exp(-x)); exp via exp2, fast rcp (exact at +-inf limits)
__device__ __forceinline__ float sig_fast(float x) {
    return __builtin_amdgcn_rcpf(1.f + ex2(-1.44269504088896f * x));
}
// tanh(x) = 1 - 2/(exp(2x)+1); exact at +-inf limits
__device__ __forceinline__ float tanh_fast(float x) {
    return 1.f - 2.f * __builtin_amdgcn_rcpf(ex2(2.88539008177793f * x) + 1.f);
}

// ---------------------------------------------------------------------------
// Kernel 0: weight prep (chunk-major layout, unchanged from round 9).
//   Wr[t][g][chunk 36][och 64][k 32],  chunk = tap*4 + ci/32, k = ci%32
//   Wp[g][chunk 24][och 64][k 32],     chunk = ci/32 (768 ci)
// ---------------------------------------------------------------------------
__global__ __launch_bounds__(256) void prep_kernel(
    const float* __restrict__ Wq, const float* __restrict__ Wk,
    const float* __restrict__ Wv, const float* __restrict__ Wix,
    const float* __restrict__ Wfx, const float* __restrict__ Wgx,
    const float* __restrict__ Wox, const float* __restrict__ Wia,
    const float* __restrict__ Wfa, const float* __restrict__ Wga,
    const float* __restrict__ Woa, const float* __restrict__ Wx,
    const float* __restrict__ Wig,
    __hip_bfloat16* __restrict__ Wr, __hip_bfloat16* __restrict__ Wa,
    __hip_bfloat16* __restrict__ Wp)
{
    const int i = blockIdx.x * 256 + threadIdx.x;
    const int N1 = 7 * WRT;
    const int N2 = N1 + 4 * 32768;
    if (i < N1) {
        const int t = i / WRT, r = i % WRT;
        const int g = r / 73728, r2 = r % 73728;
        const int chunk = r2 / 2048, r3 = r2 % 2048;
        const int och = r3 / 32, k = r3 % 32;
        const int tap = chunk >> 2;
        const int ci = (chunk & 3) * 32 + k;
        const int co = g * 64 + och;
        const float* src;
        switch (t) {
            case 0: src = Wq;  break;  case 1: src = Wk;  break;
            case 2: src = Wv;  break;  case 3: src = Wix; break;
            case 4: src = Wfx; break;  case 5: src = Wgx; break;
            default: src = Wox;
        }
        Wr[i] = (__hip_bfloat16)src[(size_t)co * 1152 + ci * 9 + tap];
    } else if (i < N2) {
        const int j = i - N1;
        const int t = j / 32768, r = j % 32768;
        const float* src = (t == 0) ? Wia : (t == 1) ? Wfa : (t == 2) ? Wga : Woa;
        Wa[j] = (__hip_bfloat16)src[r];
    } else {
        const int j = i - N2;                // 0..393215
        const int g = j / 49152, r = j % 49152;
        const int chunk = r / 2048, r3 = r % 2048;
        const int och = r3 / 32, k = r3 % 32;
        const int c = g * 64 + och;
        const int ci = chunk * 32 + k;
        Wp[j] = (__hip_bfloat16)((ci < 256) ? Wx[(size_t)c * 256 + ci]
                                            : Wig[(size_t)c * 512 + (ci - 256)]);
    }
}

// ---------------------------------------------------------------------------
// Kernel 1a: transpose/convert (unchanged).
// ---------------------------------------------------------------------------
__global__ __launch_bounds__(256) void xpose_kernel(
    const float* __restrict__ x_in, const float* __restrict__ h,
    __hip_bfloat16* __restrict__ xiT, __hip_bfloat16* __restrict__ xhT)
{
    const int pt = blockIdx.x;
    const int n  = blockIdx.y;
    const int p0 = pt * 16;
    const int tid = threadIdx.x;

    __shared__ float xs[CIN * 17];
    __shared__ float hs[CC * 17];

    const float* xb = x_in + (size_t)n * CIN * PP;
    const float* hb = h + (size_t)n * CC * PP;
    #pragma unroll
    for (int k = 0; k < 16; ++k) {
        const int idx = k * 256 + tid;
        xs[(idx >> 4) * 17 + (idx & 15)] = xb[(size_t)(idx >> 4) * PP + p0 + (idx & 15)];
    }
    #pragma unroll
    for (int k = 0; k < 32; ++k) {
        const int idx = k * 256 + tid;
        hs[(idx >> 4) * 17 + (idx & 15)] = hb[(size_t)(idx >> 4) * PP + p0 + (idx & 15)];
    }
    __syncthreads();

    #pragma unroll
    for (int it = 0; it < 2; ++it) {
        const int u = it * 256 + tid;
        const int pix = u & 15, ck = u >> 4;
        union { __hip_bfloat16 h8[8]; bf16x8 v; } t;
        #pragma unroll
        for (int j = 0; j < 8; ++j)
            t.h8[j] = (__hip_bfloat16)xs[(ck * 8 + j) * 17 + pix];
        *reinterpret_cast<bf16x8*>(
            xiT + ((size_t)n * PP + p0 + pix) * 256 + ck * 8) = t.v;
    }
    #pragma unroll
    for (int it = 0; it < 4; ++it) {
        const int u = it * 256 + tid;
        const int pix = u & 15, ck = u >> 4;
        const int g = ck >> 3, c8 = (ck & 7) * 8;
        union { __hip_bfloat16 h8[8]; bf16x8 v; } t;
        #pragma unroll
        for (int j = 0; j < 8; ++j)
            t.h8[j] = (__hip_bfloat16)hs[(ck * 8 + j) * 17 + pix];
        *reinterpret_cast<bf16x8*>(
            xhT + ((size_t)(n * GG + g) * PP + p0 + pix) * 128 + 64 + c8) = t.v;
    }
}

// ---------------------------------------------------------------------------
// Kernel 1b: proj GEMM via MFMA. Chunk-major Wp addressing (round-9 form,
// split reverted: it duplicated B loads). grid 192 x 256.
// ---------------------------------------------------------------------------
__global__ __launch_bounds__(256) void proj_mfma_kernel(
    const __hip_bfloat16* __restrict__ xiT, const __hip_bfloat16* __restrict__ Wp,
    __hip_bfloat16* xhT)
{
    const int b = blockIdx.x;
    const int g = b & 7;
    const int j = b >> 3;
    const int n = j / 12;
    const int yt = j % 12;
    const int ng = n * GG + g;
    const int tid = threadIdx.x;
    const int w = tid >> 6, lane = tid & 63;
    const int col = lane & 15, quad = lane >> 4;
    const int y = yt * 4 + w;

    f32x4 acc[12];
    #pragma unroll
    for (int i = 0; i < 12; ++i) acc[i] = (f32x4){0.f, 0.f, 0.f, 0.f};

    const __hip_bfloat16* wgbase = Wp + (size_t)g * 24 * 2048 + col * 32 + quad * 8;

    for (int kk = 0; kk < 24; ++kk) {
        bf16x8 bfr[3];
        if (kk < 8) {
            const __hip_bfloat16* bp =
                xiT + ((size_t)n * PP + y * 48 + col) * 256 + kk * 32 + quad * 8;
            #pragma unroll
            for (int nf = 0; nf < 3; ++nf)
                bfr[nf] = ldb8(bp + (size_t)(nf * 16) * 256);
        } else {
            const int kh = kk - 8;
            const int gp = kh >> 1;
            const int c0 = (kh & 1) * 32;
            const __hip_bfloat16* bp =
                xhT + ((size_t)(n * GG + gp) * PP + y * 48 + col) * 128 + 64 + c0 + quad * 8;
            #pragma unroll
            for (int nf = 0; nf < 3; ++nf)
                bfr[nf] = ldb8(bp + (size_t)(nf * 16) * 128);
        }
        const __hip_bfloat16* wp = wgbase + kk * 2048;
        #pragma unroll
        for (int cf = 0; cf < 4; ++cf) {
            const bf16x8 af = ldb8(wp + cf * 512);
            #pragma unroll
            for (int nf = 0; nf < 3; ++nf)
                acc[cf * 3 + nf] = __builtin_amdgcn_mfma_f32_16x16x32_bf16(
                    af, bfr[nf], acc[cf * 3 + nf], 0, 0, 0);
        }
    }

    __hip_bfloat16* dst = xhT + (size_t)ng * PP * 128;
    #pragma unroll
    for (int cf = 0; cf < 4; ++cf)
        #pragma unroll
        for (int nf = 0; nf < 3; ++nf) {
            const int pix = y * 48 + nf * 16 + col;
            store4bf(dst + (size_t)pix * 128 + cf * 16 + quad * 4, acc[cf * 3 + nf]);
        }
}

// ---------------------------------------------------------------------------
// Kernel 2: fused q/k/v grouped 3x3 conv via MFMA.
// V OUTPUT NOW CHUNK-MAJOR: v[ng][chunk=d/32][co 64][dk=d%32]; 4-key tail
// (d 2112..2115) stored compactly at VTAIL + co*8 + (d-2112), with slots
// 4..7 explicitly zeroed so attn's tail MFMA reads finite zeros.
// grid 576 x 512.
// ---------------------------------------------------------------------------
__global__ __launch_bounds__(512) void conv_qkv_kernel(
    const __hip_bfloat16* __restrict__ xhT, const __hip_bfloat16* __restrict__ Wr,
    const float* __restrict__ tau,
    __hip_bfloat16* __restrict__ qT, __hip_bfloat16* __restrict__ kT,
    __hip_bfloat16* __restrict__ v)
{
    const int b = blockIdx.x;                // 0..575
    const int xcd = b & 7;
    const int j = b >> 3;
    const int s = xcd + 8 * (j / 12);
    const int yt = j % 12;
    const int t = s / 16;
    const int ng = s % 16;
    const int g = ng & 7;
    const int tid = threadIdx.x;
    const int w8 = tid >> 6, lane = tid & 63;
    const int yw = w8 & 3, chalf = w8 >> 2;
    const int cf0 = chalf * 2;
    const int col = lane & 15, quad = lane >> 4;
    const int y0 = yt * 4;
    const int yy = y0 + yw;
    const int ohw = (t == 0) ? 48 : 46;
    const int d0 = (t == 0) ? -1 : 0;
    const int soff = (t == 0) ? 1 : 0;       // stage column offset
    const bool wave_active = (yy < ohw);

    __shared__ __hip_bfloat16 st[8 * 300 * 8];   // [ck][lr*50+sc] x 8 bf16

    const __hip_bfloat16* slab = xhT + (size_t)ng * PP * 128;
    const __hip_bfloat16* wgbase =
        Wr + ((size_t)t * 8 + g) * 36 * 2048 + col * 32 + quad * 8;

    // zero the pad columns once (never overwritten by data stages)
    if (tid < 96) {
        const int ck = tid / 12, r2 = tid % 12;
        const int lr = r2 >> 1, side = r2 & 1;
        const int sc = side ? 49 : (soff ? 0 : 48);
        *reinterpret_cast<bf16x8*>(st + ((ck * 300) + lr * 50 + sc) * 8) =
            (bf16x8)(__bf16)0.f;
    }

    f32x4 acc[6];
    #pragma unroll
    for (int i = 0; i < 6; ++i) acc[i] = (f32x4){0.f, 0.f, 0.f, 0.f};

    for (int hc = 0; hc < 2; ++hc) {
        __syncthreads();
        #pragma unroll
        for (int it = 0; it < 5; ++it) {
            const int u = it * 512 + tid;
            if (u < 2304) {
                const int lr = u / 384;
                const int rem = u % 384;
                const int px = rem >> 3, ck = rem & 7;
                const int ry = y0 + d0 + lr;
                const int ryc = max(0, min(47, ry));
                bf16x8 vv = ldb8(slab + ((size_t)(ryc * 48 + px)) * 128 + hc * 64 + ck * 8);
                *reinterpret_cast<bf16x8*>(st + ((ck * 300) + lr * 50 + px + soff) * 8) =
                    (ry == ryc) ? vv : (bf16x8)(__bf16)0.f;
            }
        }
        __syncthreads();
        if (!wave_active) continue;

        #pragma unroll
        for (int ky = 0; ky < 3; ++ky) {
            const int lrk = (yw + ky) * 50;
            #pragma unroll
            for (int kx = 0; kx < 3; ++kx) {
                const int scb = col + kx;
                #pragma unroll
                for (int c32 = 0; c32 < 2; ++c32) {
                    bf16x8 bfr[3];
                    #pragma unroll
                    for (int nf = 0; nf < 3; ++nf)
                        bfr[nf] = *reinterpret_cast<const bf16x8*>(
                            st + (((c32 * 4 + quad) * 300) + lrk + nf * 16 + scb) * 8);
                    const __hip_bfloat16* wp =
                        wgbase + ((ky * 3 + kx) * 4 + hc * 2 + c32) * 2048;
                    if (t != 2) {
                        #pragma unroll
                        for (int cc = 0; cc < 2; ++cc) {
                            const bf16x8 af = ldb8(wp + (cf0 + cc) * 512);
                            #pragma unroll
                            for (int nf = 0; nf < 3; ++nf)
                                acc[cc * 3 + nf] = __builtin_amdgcn_mfma_f32_16x16x32_bf16(
                                    af, bfr[nf], acc[cc * 3 + nf], 0, 0, 0);
                        }
                    } else {
                        #pragma unroll
                        for (int cc = 0; cc < 2; ++cc) {
                            const bf16x8 af = ldb8(wp + (cf0 + cc) * 512);
                            #pragma unroll
                            for (int nf = 0; nf < 3; ++nf)
                                acc[cc * 3 + nf] = __builtin_amdgcn_mfma_f32_16x16x32_bf16(
                                    bfr[nf], af, acc[cc * 3 + nf], 0, 0, 0);
                        }
                    }
                }
            }
        }
    }

    if (!wave_active) return;
    if (t == 0) {
        const float ts = tau[g] * 1.44269504088896340736f;  // fold log2(e)
        __hip_bfloat16* dst = qT + (size_t)ng * PP * 64;
        #pragma unroll
        for (int cc = 0; cc < 2; ++cc)
            #pragma unroll
            for (int nf = 0; nf < 3; ++nf) {
                const int pix = yy * 48 + nf * 16 + col;
                store4bf(dst + (size_t)pix * 64 + (cf0 + cc) * 16 + quad * 4,
                         acc[cc * 3 + nf] * ts);
            }
    } else if (t == 1) {
        __hip_bfloat16* dst = kT + (size_t)ng * DD * 64;
        #pragma unroll
        for (int cc = 0; cc < 2; ++cc)
            #pragma unroll
            for (int nf = 0; nf < 3; ++nf) {
                const int x = nf * 16 + col;
                if (x < 46) {
                    const int pix = yy * 46 + x;
                    store4bf(dst + (size_t)pix * 64 + (cf0 + cc) * 16 + quad * 4,
                             acc[cc * 3 + nf]);
                }
            }
    } else {
        __hip_bfloat16* dst = v + (size_t)ng * VSTRIDE;
        #pragma unroll
        for (int cc = 0; cc < 2; ++cc) {
            const int co = (cf0 + cc) * 16 + col;
            #pragma unroll
            for (int nf = 0; nf < 3; ++nf) {
                const int x4 = nf * 16 + quad * 4;
                #pragma unroll
                for (int r = 0; r < 4; ++r) {
                    const int x = x4 + r;
                    if (x < 46) {
                        const int d = yy * 46 + x;
                        const int addr = (d < 2112)
                            ? ((d >> 5) * 2048 + co * 32 + (d & 31))
                            : (VTAIL + co * 8 + (d - 2112));
                        dst[addr] = (__hip_bfloat16)acc[cc * 3 + nf][r];
                    }
                }
            }
            // zero tail slots 4..7 (read by attn tail MFMA with P==0)
            if (yy == 45 && quad == 0) {
                #pragma unroll
                for (int jz = 4; jz < 8; ++jz)
                    dst[VTAIL + co * 8 + jz] = (__hip_bfloat16)0.f;
            }
        }
    }
}

// ---------------------------------------------------------------------------
// Kernel 3: MFMA flash attention (round-9 two-q-tile form).
// V loads now CHUNK-MAJOR: one 1KB-contiguous span per instruction
// (was a 16-line gather with per-lane stride 4240B). grid 1152 x 256.
// ---------------------------------------------------------------------------
__global__ __launch_bounds__(256) void attn_kernel(
    __hip_bfloat16* qa,                      // qT in (tau*log2e-scaled), aT out
    const __hip_bfloat16* __restrict__ kT,
    const __hip_bfloat16* __restrict__ vT)
{
    const int idx = blockIdx.x;              // 0..1151, idx&7 = group (XCD affinity)
    const int j3  = idx >> 3;                // 0..143
    const int sub = (j3 >= 72) ? 1 : 0;
    const int ng  = (idx & 7) + 8 * sub;
    const int qt  = j3 - 72 * sub;           // 0..71
    const int tid = threadIdx.x;
    const int w = tid >> 6, lane = tid & 63;
    const int col = lane & 15, quad = lane >> 4;
    const int qbase = qt * 32;

    // per-wave key-chunk: [it0, it1) full 32-key tiles; w==3 also does tail
    const int it0 = w * 17;
    const int it1 = (w < 3) ? (it0 + 17) : 66;

    __shared__ float lmS[3][2][64];
    __shared__ float llS[3][2][64];
    __shared__ float laccS[3][2][64][16];

    __hip_bfloat16* qrowA = qa + ((size_t)ng * PP + qbase + col) * CGR;
    __hip_bfloat16* qrowB = qrowA + 16 * CGR;
    const bf16x8 qfA0 = ldb8(qrowA + quad * 8);
    const bf16x8 qfA1 = ldb8(qrowA + 32 + quad * 8);
    const bf16x8 qfB0 = ldb8(qrowB + quad * 8);
    const bf16x8 qfB1 = ldb8(qrowB + 32 + quad * 8);

    const __hip_bfloat16* kbase = kT + (size_t)ng * DD * CGR;
    const __hip_bfloat16* vbase = vT + (size_t)ng * VSTRIDE;

    // permuted tile-local key for this lane's A-rows
    const int key0 = ((col >> 2) << 3) + (col & 3);
    const __hip_bfloat16* p0 = kbase + (size_t)(it0 * 32 + key0) * CGR + quad * 8;
    const __hip_bfloat16* p1 = p0 + 4 * CGR;

    f32x4 accA[4], accB[4];
    #pragma unroll
    for (int cf = 0; cf < 4; ++cf) {
        accA[cf] = (f32x4){0.f, 0.f, 0.f, 0.f};
        accB[cf] = (f32x4){0.f, 0.f, 0.f, 0.f};
    }
    float mA = -INFINITY, mB = -INFINITY;    // col-uniform running max (exp2 dom)
    float lA = 0.f, lB = 0.f;                // PER-LANE partial denominators
    const f32x4 zero = {0.f, 0.f, 0.f, 0.f};

    for (int it = it0; it < it1; ++it) {
        const bf16x8 K0a = ldb8(p0), K0b = ldb8(p0 + 32);
        const bf16x8 K1a = ldb8(p1), K1b = ldb8(p1 + 32);
        p0 += 32 * CGR; p1 += 32 * CGR;

        f32x4 SA0 = __builtin_amdgcn_mfma_f32_16x16x32_bf16(K0a, qfA0, zero, 0, 0, 0);
        SA0 = __builtin_amdgcn_mfma_f32_16x16x32_bf16(K0b, qfA1, SA0, 0, 0, 0);
        f32x4 SA1 = __builtin_amdgcn_mfma_f32_16x16x32_bf16(K1a, qfA0, zero, 0, 0, 0);
        SA1 = __builtin_amdgcn_mfma_f32_16x16x32_bf16(K1b, qfA1, SA1, 0, 0, 0);
        f32x4 SB0 = __builtin_amdgcn_mfma_f32_16x16x32_bf16(K0a, qfB0, zero, 0, 0, 0);
        SB0 = __builtin_amdgcn_mfma_f32_16x16x32_bf16(K0b, qfB1, SB0, 0, 0, 0);
        f32x4 SB1 = __builtin_amdgcn_mfma_f32_16x16x32_bf16(K1a, qfB0, zero, 0, 0, 0);
        SB1 = __builtin_amdgcn_mfma_f32_16x16x32_bf16(K1b, qfB1, SB1, 0, 0, 0);

        // V loads: chunk-major, 1KB contiguous per instruction; latency
        // hides under the softmax chain
        const __hip_bfloat16* vp = vbase + it * 2048 + col * 32 + quad * 8;
        const bf16x8 vf0 = ldb8(vp);
        const bf16x8 vf1 = ldb8(vp + 512);
        const bf16x8 vf2 = ldb8(vp + 1024);
        const bf16x8 vf3 = ldb8(vp + 1536);

        const float lmAx = fmaxf(fmaxf(fmaxf(SA0[0], SA0[1]), fmaxf(SA0[2], SA0[3])),
                                 fmaxf(fmaxf(SA1[0], SA1[1]), fmaxf(SA1[2], SA1[3])));
        const float lmBx = fmaxf(fmaxf(fmaxf(SB0[0], SB0[1]), fmaxf(SB0[2], SB0[3])),
                                 fmaxf(fmaxf(SB1[0], SB1[1]), fmaxf(SB1[2], SB1[3])));

        if (__any((lmAx > mA + 8.f) || (lmBx > mB + 8.f))) {
            // rare path: full cross-lane max reduce + rescale
            float sA = lmAx;
            sA = fmaxf(sA, __shfl_xor(sA, 16, 64));
            sA = fmaxf(sA, __shfl_xor(sA, 32, 64));
            float sB = lmBx;
            sB = fmaxf(sB, __shfl_xor(sB, 16, 64));
            sB = fmaxf(sB, __shfl_xor(sB, 32, 64));
            const float mnA = fmaxf(mA, sA), mnB = fmaxf(mB, sB);
            const float aA = ex2(mA - mnA), aB = ex2(mB - mnB);
            lA *= aA; lB *= aB;
            #pragma unroll
            for (int cf = 0; cf < 4; ++cf) { accA[cf] *= aA; accB[cf] *= aB; }
            mA = mnA; mB = mnB;
        }

        float eA[8], eB[8];
        float lsA = 0.f, lsB = 0.f;
        #pragma unroll
        for (int r = 0; r < 4; ++r) {
            eA[r]     = ex2(SA0[r] - mA);
            eA[4 + r] = ex2(SA1[r] - mA);
            eB[r]     = ex2(SB0[r] - mB);
            eB[4 + r] = ex2(SB1[r] - mB);
            lsA += eA[r] + eA[4 + r];
            lsB += eB[r] + eB[4 + r];
        }
        lA += lsA; lB += lsB;

        bf16x8 ptA, ptB;
        #pragma unroll
        for (int jj = 0; jj < 8; ++jj) { ptA[jj] = (__bf16)eA[jj]; ptB[jj] = (__bf16)eB[jj]; }

        accA[0] = __builtin_amdgcn_mfma_f32_16x16x32_bf16(vf0, ptA, accA[0], 0, 0, 0);
        accB[0] = __builtin_amdgcn_mfma_f32_16x16x32_bf16(vf0, ptB, accB[0], 0, 0, 0);
        accA[1] = __builtin_amdgcn_mfma_f32_16x16x32_bf16(vf1, ptA, accA[1], 0, 0, 0);
        accB[1] = __builtin_amdgcn_mfma_f32_16x16x32_bf16(vf1, ptB, accB[1], 0, 0, 0);
        accA[2] = __builtin_amdgcn_mfma_f32_16x16x32_bf16(vf2, ptA, accA[2], 0, 0, 0);
        accB[2] = __builtin_amdgcn_mfma_f32_16x16x32_bf16(vf2, ptB, accB[2], 0, 0, 0);
        accA[3] = __builtin_amdgcn_mfma_f32_16x16x32_bf16(vf3, ptA, accA[3], 0, 0, 0);
        accB[3] = __builtin_amdgcn_mfma_f32_16x16x32_bf16(vf3, ptB, accB[3], 0, 0, 0);
    }

    // ---- masked tail tile (w==3 only): keys 2112..2143, valid < 2116 ----
    if (w == 3) {
        const int dbase = 66 * 32;
        const int kk0 = min(dbase + key0, DD - 1);
        const int kk1 = min(dbase + key0 + 4, DD - 1);
        const __hip_bfloat16* t0 = kbase + (size_t)kk0 * CGR + quad * 8;
        const __hip_bfloat16* t1 = kbase + (size_t)kk1 * CGR + quad * 8;
        const bf16x8 Ka = ldb8(t0), Kb = ldb8(t0 + 32);
        const bf16x8 Kc = ldb8(t1), Kd = ldb8(t1 + 32);

        f32x4 SA0 = __builtin_amdgcn_mfma_f32_16x16x32_bf16(Ka, qfA0, zero, 0, 0, 0);
        SA0 = __builtin_amdgcn_mfma_f32_16x16x32_bf16(Kb, qfA1, SA0, 0, 0, 0);
        f32x4 SA1 = __builtin_amdgcn_mfma_f32_16x16x32_bf16(Kc, qfA0, zero, 0, 0, 0);
        SA1 = __builtin_amdgcn_mfma_f32_16x16x32_bf16(Kd, qfA1, SA1, 0, 0, 0);
        f32x4 SB0 = __builtin_amdgcn_mfma_f32_16x16x32_bf16(Ka, qfB0, zero, 0, 0, 0);
        SB0 = __builtin_amdgcn_mfma_f32_16x16x32_bf16(Kb, qfB1, SB0, 0, 0, 0);
        f32x4 SB1 = __builtin_amdgcn_mfma_f32_16x16x32_bf16(Kc, qfB0, zero, 0, 0, 0);
        SB1 = __builtin_amdgcn_mfma_f32_16x16x32_bf16(Kd, qfB1, SB1, 0, 0, 0);

        float eA[8], eB[8];
        #pragma unroll
        for (int r = 0; r < 4; ++r) {
            const bool v0 = (dbase + quad * 8 + r     < DD);
            const bool v1 = (dbase + quad * 8 + 4 + r < DD);
            eA[r]     = v0 ? SA0[r] : -1e30f;
            eA[4 + r] = v1 ? SA1[r] : -1e30f;
            eB[r]     = v0 ? SB0[r] : -1e30f;
            eB[4 + r] = v1 ? SB1[r] : -1e30f;
        }
        float sA = fmaxf(fmaxf(fmaxf(eA[0], eA[1]), fmaxf(eA[2], eA[3])),
                         fmaxf(fmaxf(eA[4], eA[5]), fmaxf(eA[6], eA[7])));
        sA = fmaxf(sA, __shfl_xor(sA, 16, 64));
        sA = fmaxf(sA, __shfl_xor(sA, 32, 64));
        float sB = fmaxf(fmaxf(fmaxf(eB[0], eB[1]), fmaxf(eB[2], eB[3])),
                         fmaxf(fmaxf(eB[4], eB[5]), fmaxf(eB[6], eB[7])));
        sB = fmaxf(sB, __shfl_xor(sB, 16, 64));
        sB = fmaxf(sB, __shfl_xor(sB, 32, 64));
        const float mnA = fmaxf(mA, sA), mnB = fmaxf(mB, sB);
        const float aA = ex2(mA - mnA), aB = ex2(mB - mnB);
        float lsA = 0.f, lsB = 0.f;
        #pragma unroll
        for (int jj = 0; jj < 8; ++jj) {
            eA[jj] = ex2(eA[jj] - mnA); lsA += eA[jj];
            eB[jj] = ex2(eB[jj] - mnB); lsB += eB[jj];
        }
        lA = lA * aA + lsA;
        lB = lB * aB + lsB;
        mA = mnA; mB = mnB;

        bf16x8 ptA, ptB;
        #pragma unroll
        for (int jj = 0; jj < 8; ++jj) { ptA[jj] = (__bf16)eA[jj]; ptB[jj] = (__bf16)eB[jj]; }

        // V tail: quad 0 reads compact tail (4 valid + 4 zeros); other quads
        // read chunk 0 (finite) but their P entries are exactly 0.
        #pragma unroll
        for (int cf = 0; cf < 4; ++cf) {
            const int co = cf * 16 + col;
            const int taddr = (quad == 0) ? (VTAIL + co * 8) : 0;
            const bf16x8 vf = ldb8(vbase + taddr);
            accA[cf] *= aA; accB[cf] *= aB;
            accA[cf] = __builtin_amdgcn_mfma_f32_16x16x32_bf16(vf, ptA, accA[cf], 0, 0, 0);
            accB[cf] = __builtin_amdgcn_mfma_f32_16x16x32_bf16(vf, ptB, accB[cf], 0, 0, 0);
        }
    }

    // ---- cross-wave merge of (m, l, acc) partials via LDS ----
    if (w != 0) {
        lmS[w - 1][0][lane] = mA; lmS[w - 1][1][lane] = mB;
        llS[w - 1][0][lane] = lA; llS[w - 1][1][lane] = lB;
        #pragma unroll
        for (int cf = 0; cf < 4; ++cf) {
            *reinterpret_cast<f32x4*>(&laccS[w - 1][0][lane][cf * 4]) = accA[cf];
            *reinterpret_cast<f32x4*>(&laccS[w - 1][1][lane][cf * 4]) = accB[cf];
        }
    }
    __syncthreads();
    if (w != 0) return;

    #pragma unroll
    for (int ww = 0; ww < 3; ++ww) {
        {
            const float mo = lmS[ww][0][lane];
            const float lo = llS[ww][0][lane];
            const float mn = fmaxf(mA, mo);
            const float a0 = ex2(mA - mn);
            const float a1 = ex2(mo - mn);
            lA = lA * a0 + lo * a1;
            #pragma unroll
            for (int cf = 0; cf < 4; ++cf) {
                const f32x4 o = *reinterpret_cast<const f32x4*>(&laccS[ww][0][lane][cf * 4]);
                accA[cf] = accA[cf] * a0 + o * a1;
            }
            mA = mn;
        }
        {
            const float mo = lmS[ww][1][lane];
            const float lo = llS[ww][1][lane];
            const float mn = fmaxf(mB, mo);
            const float a0 = ex2(mB - mn);
            const float a1 = ex2(mo - mn);
            lB = lB * a0 + lo * a1;
            #pragma unroll
            for (int cf = 0; cf < 4; ++cf) {
                const f32x4 o = *reinterpret_cast<const f32x4*>(&laccS[ww][1][lane][cf * 4]);
                accB[cf] = accB[cf] * a0 + o * a1;
            }
            mB = mn;
        }
    }

    // single cross-lane reduce of the per-lane partial denominators
    lA += __shfl_xor(lA, 16, 64);
    lA += __shfl_xor(lA, 32, 64);
    lB += __shfl_xor(lB, 16, 64);
    lB += __shfl_xor(lB, 32, 64);

    const float invA = 1.f / lA;
    const float invB = 1.f / lB;
    #pragma unroll
    for (int cf = 0; cf < 4; ++cf) {
        store4bf(qrowA + cf * 16 + quad * 4, accA[cf] * invA);
        store4bf(qrowB + cf * 16 + quad * 4, accB[cf] * invB);
    }
}

// ---------------------------------------------------------------------------
// Kernel 4: fused gates via MFMA + LSTM update (unchanged from round 9).
// grid 768 x 512.
// ---------------------------------------------------------------------------
__global__ __launch_bounds__(512) void gates_kernel(
    const __hip_bfloat16* __restrict__ xhT, const __hip_bfloat16* __restrict__ aT,
    const float* __restrict__ c_in,
    const __hip_bfloat16* __restrict__ Wr, const __hip_bfloat16* __restrict__ Wa,
    const float* __restrict__ b_i, const float* __restrict__ b_f,
    const float* __restrict__ b_g, const float* __restrict__ b_o,
    float* __restrict__ h_out)
{
    const int b = blockIdx.x;                // 0..767
    const int xcd = b & 7;
    const int j = b >> 3;                    // 0..95
    const int ng = xcd + 8 * (j / 48);
    const int yy = j % 48;
    const int n = ng >> 3, g = ng & 7;
    const int tid = threadIdx.x;
    const int w8 = tid >> 6, lane = tid & 63;
    const int gate = w8 & 3, chalf = w8 >> 2;
    const int cf0 = chalf * 2;
    const int col = lane & 15, quad = lane >> 4;

    __shared__ char smem[38400];             // max(stage 38400, exchange 24576)
    __hip_bfloat16* st = (__hip_bfloat16*)smem;
    float* ex = (float*)smem;

    const __hip_bfloat16* slab = xhT + (size_t)ng * PP * 128;

    // zero pad columns (sc = 0 and 49)
    if (tid < 96) {
        const int ck = tid / 6, r2 = tid % 6;
        const int lr = r2 >> 1, side = r2 & 1;
        const int sc = side ? 49 : 0;
        *reinterpret_cast<bf16x8*>(st + ((ck * 150) + lr * 50 + sc) * 8) =
            (bf16x8)(__bf16)0.f;
    }
    // stage 3 rows x 48 px x 16 ck, zeroing OOB rows; data at sc = px+1
    #pragma unroll
    for (int it = 0; it < 5; ++it) {
        const int u = it * 512 + tid;
        if (u < 2304) {
            const int lr = u / 768;
            const int rem = u % 768;
            const int px = rem >> 4, ck = rem & 15;
            const int ry = yy - 1 + lr;
            const int ryc = max(0, min(47, ry));
            bf16x8 vv = ldb8(slab + ((size_t)(ryc * 48 + px)) * 128 + ck * 8);
            *reinterpret_cast<bf16x8*>(st + ((ck * 150) + lr * 50 + px + 1) * 8) =
                (ry == ryc) ? vv : (bf16x8)(__bf16)0.f;
        }
    }
    __syncthreads();

    f32x4 acc[6];
    #pragma unroll
    for (int i = 0; i < 6; ++i) acc[i] = (f32x4){0.f, 0.f, 0.f, 0.f};

    const __hip_bfloat16* wgbase =
        Wr + ((size_t)(3 + gate) * 8 + g) * 36 * 2048 + col * 32 + quad * 8;

    #pragma unroll
    for (int ky = 0; ky < 3; ++ky) {
        const int lrk = ky * 50;
        #pragma unroll
        for (int kx = 0; kx < 3; ++kx) {
            const int scb = col + kx;
            #pragma unroll
            for (int c32 = 0; c32 < 4; ++c32) {
                bf16x8 bfr[3];
                #pragma unroll
                for (int nf = 0; nf < 3; ++nf)
                    bfr[nf] = *reinterpret_cast<const bf16x8*>(
                        st + (((c32 * 4 + quad) * 150) + lrk + nf * 16 + scb) * 8);
                const __hip_bfloat16* wp =
                    wgbase + ((ky * 3 + kx) * 4 + c32) * 2048;
                #pragma unroll
                for (int cc = 0; cc < 2; ++cc) {
                    const bf16x8 af = ldb8(wp + (cf0 + cc) * 512);
                    #pragma unroll
                    for (int nf = 0; nf < 3; ++nf)
                        acc[cc * 3 + nf] = __builtin_amdgcn_mfma_f32_16x16x32_bf16(
                            af, bfr[nf], acc[cc * 3 + nf], 0, 0, 0);
                }
            }
        }
    }

    {
        const __hip_bfloat16* wa =
            Wa + (size_t)gate * 32768 + ((size_t)(g * 64) + col) * 64;
        const __hip_bfloat16* ab = aT + ((size_t)ng * PP + yy * 48) * 64;
        #pragma unroll
        for (int c32 = 0; c32 < 2; ++c32) {
            bf16x8 bfr[3];
            #pragma unroll
            for (int nf = 0; nf < 3; ++nf)
                bfr[nf] = ldb8(ab + (size_t)(nf * 16 + col) * 64 + c32 * 32 + quad * 8);
            #pragma unroll
            for (int cc = 0; cc < 2; ++cc) {
                const bf16x8 af = ldb8(wa + (size_t)((cf0 + cc) * 16) * 64 + c32 * 32 + quad * 8);
                #pragma unroll
                for (int nf = 0; nf < 3; ++nf)
                    acc[cc * 3 + nf] = __builtin_amdgcn_mfma_f32_16x16x32_bf16(
                        af, bfr[nf], acc[cc * 3 + nf], 0, 0, 0);
            }
        }
    }

    const float* bias = (gate == 0) ? b_i : (gate == 1) ? b_f : (gate == 2) ? b_g : b_o;
    #pragma unroll
    for (int cc = 0; cc < 2; ++cc) {
        #pragma unroll
        for (int r = 0; r < 4; ++r) {
            const float bv = bias[g * 64 + (cf0 + cc) * 16 + quad * 4 + r];
            #pragma unroll
            for (int nf = 0; nf < 3; ++nf)
                acc[cc * 3 + nf][r] += bv;
        }
    }

    for (int hh = 0; hh < 2; ++hh) {
        __syncthreads();
        if (chalf == hh) {
            #pragma unroll
            for (int cc = 0; cc < 2; ++cc)
                #pragma unroll
                for (int nf = 0; nf < 3; ++nf)
                    #pragma unroll
                    for (int r = 0; r < 4; ++r)
                        ex[(size_t)gate * 1536 + (cc * 16 + quad * 4 + r) * 48 + nf * 16 + col] =
                            acc[cc * 3 + nf][r];
        }
        __syncthreads();
        #pragma unroll
        for (int k2 = 0; k2 < 3; ++k2) {
            const int idx = k2 * 512 + tid;
            const int co32 = idx / 48, px = idx % 48;
            const float iv = ex[0 * 1536 + co32 * 48 + px];
            const float fv = ex[1 * 1536 + co32 * 48 + px];
            const float gv = ex[2 * 1536 + co32 * 48 + px];
            const float ov = ex[3 * 1536 + co32 * 48 + px];
            const int c = g * 64 + hh * 32 + co32;
            const size_t off = ((size_t)n * CC + c) * PP + yy * 48 + px;
            const float ig = sig_fast(iv);
            const float fg = sig_fast(fv);
            const float gg = tanh_fast(gv);
            const float og = sig_fast(ov);
            const float cn = fg * c_in[off] + ig * gg;
            h_out[off] = og * tanh_fast(cn);
        }
    }
}

// ---------------------------------------------------------------------------
extern "C" void kernel_launch(void* const* d_in, const int* in_sizes, int n_in,
                              void* d_out, int out_size, void* d_ws, size_t ws_size,
                              hipStream_t stream)
{
    const float* x_in = (const float*)d_in[0];
    const float* h    = (const float*)d_in[1];
    const float* c    = (const float*)d_in[2];
    const float* tau  = (const float*)d_in[3];
    const float* W_x  = (const float*)d_in[4];
    const float* W_ig = (const float*)d_in[5];
    const float* W_q  = (const float*)d_in[6];
    const float* W_k  = (const float*)d_in[7];
    const float* W_v  = (const float*)d_in[8];
    const float* Wi_a = (const float*)d_in[9];
    const float* Wi_x = (const float*)d_in[10];
    const float* b_i  = (const float*)d_in[11];
    const float* Wf_a = (const float*)d_in[12];
    const float* Wf_x = (const float*)d_in[13];
    const float* b_f  = (const float*)d_in[14];
    const float* Wg_a = (const float*)d_in[15];
    const float* Wg_x = (const float*)d_in[16];
    const float* b_g  = (const float*)d_in[17];
    const float* Wo_a = (const float*)d_in[18];
    const float* Wo_x = (const float*)d_in[19];
    const float* b_o  = (const float*)d_in[20];
    float* out = (float*)d_out;

    // Workspace (bf16 elements), total 34,496,512 B (~32.9 MB)
    __hip_bfloat16* wsb = (__hip_bfloat16*)d_ws;
    __hip_bfloat16* xhT = wsb;                        // 4,718,592
    __hip_bfloat16* qa  = xhT + (size_t)4718592;      // 2,359,296
    __hip_bfloat16* kT  = qa  + (size_t)2359296;      // 2,166,784
    __hip_bfloat16* vv  = kT  + (size_t)2166784;      // 2,170,880 (16 x VSTRIDE = 2,170,880)
    __hip_bfloat16* Wr  = vv  + (size_t)2170880;      // 4,128,768
    __hip_bfloat16* Wa  = Wr  + (size_t)4128768;      //   131,072
    __hip_bfloat16* Wp  = Wa  + (size_t)131072;       //   393,216
    __hip_bfloat16* xiT = Wp  + (size_t)393216;       // 1,179,648

    dim3 blk(256);
    dim3 blk8(512);
    prep_kernel<<<dim3(18176), blk, 0, stream>>>(
        W_q, W_k, W_v, Wi_x, Wf_x, Wg_x, Wo_x, Wi_a, Wf_a, Wg_a, Wo_a,
        W_x, W_ig, Wr, Wa, Wp);
    xpose_kernel<<<dim3(144, NB), blk, 0, stream>>>(x_in, h, xiT, xhT);
    proj_mfma_kernel<<<dim3(192), blk, 0, stream>>>(xiT, Wp, xhT);
    conv_qkv_kernel<<<dim3(576), blk8, 0, stream>>>(xhT, Wr, tau, qa, kT, vv);
    attn_kernel<<<dim3(1152), blk, 0, stream>>>(qa, kT, vv);
    gates_kernel<<<dim3(768), blk8, 0, stream>>>(
        xhT, qa, c, Wr, Wa, b_i, b_f, b_g, b_o, out);
}

// Round 13
// 285.866 us; speedup vs baseline: 1.0345x; 1.0345x over previous
//
#include <hip/hip_runtime.h>
#include <hip/hip_bf16.h>
#include <math.h>

// Problem constants
#define NB   2
#define CIN  256
#define CC   512
#define GG   8
#define CGR  64
#define HH   48
#define WW   48
#define PP   (HH*WW)        // 2304
#define HD   46
#define WD   46
#define DD   (HD*WD)        // 2116
#define DPADV 2120          // v row stride (16B-aligned rows)
#define WRT  589824         // 512*9*128 = 8*36*2048, per-tensor reordered weight stride

typedef __bf16 bf16x8 __attribute__((ext_vector_type(8)));
typedef float  f32x4  __attribute__((ext_vector_type(4)));

__device__ __forceinline__ bf16x8 ldb8(const __hip_bfloat16* p) {
    return *reinterpret_cast<const bf16x8*>(p);
}
__device__ __forceinline__ void store4bf(__hip_bfloat16* p, f32x4 v) {
    union { __hip_bfloat16 h[4]; uint2 u; } t;
    #pragma unroll
    for (int r = 0; r < 4; ++r) t.h[r] = (__hip_bfloat16)v[r];
    *reinterpret_cast<uint2*>(p) = t.u;
}
__device__ __forceinline__ float ex2(float x) {
    return __builtin_amdgcn_exp2f(x);
}
// sigmoid(x) = 1/(1+exp(-x)); exp via exp2, fast rcp (exact at +-inf limits)
__device__ __forceinline__ float sig_fast(float x) {
    return __builtin_amdgcn_rcpf(1.f + ex2(-1.44269504088896f * x));
}
// tanh(x) = 1 - 2/(exp(2x)+1); exact at +-inf limits
__device__ __forceinline__ float tanh_fast(float x) {
    return 1.f - 2.f * __builtin_amdgcn_rcpf(ex2(2.88539008177793f * x) + 1.f);
}

// ---------------------------------------------------------------------------
// Kernel 0: weight prep (chunk-major layout, round-9 form).
//   Wr[t][g][chunk 36][och 64][k 32],  chunk = tap*4 + ci/32, k = ci%32
//   Wp[g][chunk 24][och 64][k 32],     chunk = ci/32 (768 ci)
// ---------------------------------------------------------------------------
__global__ __launch_bounds__(256) void prep_kernel(
    const float* __restrict__ Wq, const float* __restrict__ Wk,
    const float* __restrict__ Wv, const float* __restrict__ Wix,
    const float* __restrict__ Wfx, const float* __restrict__ Wgx,
    const float* __restrict__ Wox, const float* __restrict__ Wia,
    const float* __restrict__ Wfa, const float* __restrict__ Wga,
    const float* __restrict__ Woa, const float* __restrict__ Wx,
    const float* __restrict__ Wig,
    __hip_bfloat16* __restrict__ Wr, __hip_bfloat16* __restrict__ Wa,
    __hip_bfloat16* __restrict__ Wp)
{
    const int i = blockIdx.x * 256 + threadIdx.x;
    const int N1 = 7 * WRT;
    const int N2 = N1 + 4 * 32768;
    if (i < N1) {
        const int t = i / WRT, r = i % WRT;
        const int g = r / 73728, r2 = r % 73728;
        const int chunk = r2 / 2048, r3 = r2 % 2048;
        const int och = r3 / 32, k = r3 % 32;
        const int tap = chunk >> 2;
        const int ci = (chunk & 3) * 32 + k;
        const int co = g * 64 + och;
        const float* src;
        switch (t) {
            case 0: src = Wq;  break;  case 1: src = Wk;  break;
            case 2: src = Wv;  break;  case 3: src = Wix; break;
            case 4: src = Wfx; break;  case 5: src = Wgx; break;
            default: src = Wox;
        }
        Wr[i] = (__hip_bfloat16)src[(size_t)co * 1152 + ci * 9 + tap];
    } else if (i < N2) {
        const int j = i - N1;
        const int t = j / 32768, r = j % 32768;
        const float* src = (t == 0) ? Wia : (t == 1) ? Wfa : (t == 2) ? Wga : Woa;
        Wa[j] = (__hip_bfloat16)src[r];
    } else {
        const int j = i - N2;                // 0..393215
        const int g = j / 49152, r = j % 49152;
        const int chunk = r / 2048, r3 = r % 2048;
        const int och = r3 / 32, k = r3 % 32;
        const int c = g * 64 + och;
        const int ci = chunk * 32 + k;
        Wp[j] = (__hip_bfloat16)((ci < 256) ? Wx[(size_t)c * 256 + ci]
                                            : Wig[(size_t)c * 512 + (ci - 256)]);
    }
}

// ---------------------------------------------------------------------------
// Kernel 1a: transpose/convert (unchanged).
// ---------------------------------------------------------------------------
__global__ __launch_bounds__(256) void xpose_kernel(
    const float* __restrict__ x_in, const float* __restrict__ h,
    __hip_bfloat16* __restrict__ xiT, __hip_bfloat16* __restrict__ xhT)
{
    const int pt = blockIdx.x;
    const int n  = blockIdx.y;
    const int p0 = pt * 16;
    const int tid = threadIdx.x;

    __shared__ float xs[CIN * 17];
    __shared__ float hs[CC * 17];

    const float* xb = x_in + (size_t)n * CIN * PP;
    const float* hb = h + (size_t)n * CC * PP;
    #pragma unroll
    for (int k = 0; k < 16; ++k) {
        const int idx = k * 256 + tid;
        xs[(idx >> 4) * 17 + (idx & 15)] = xb[(size_t)(idx >> 4) * PP + p0 + (idx & 15)];
    }
    #pragma unroll
    for (int k = 0; k < 32; ++k) {
        const int idx = k * 256 + tid;
        hs[(idx >> 4) * 17 + (idx & 15)] = hb[(size_t)(idx >> 4) * PP + p0 + (idx & 15)];
    }
    __syncthreads();

    #pragma unroll
    for (int it = 0; it < 2; ++it) {
        const int u = it * 256 + tid;
        const int pix = u & 15, ck = u >> 4;
        union { __hip_bfloat16 h8[8]; bf16x8 v; } t;
        #pragma unroll
        for (int j = 0; j < 8; ++j)
            t.h8[j] = (__hip_bfloat16)xs[(ck * 8 + j) * 17 + pix];
        *reinterpret_cast<bf16x8*>(
            xiT + ((size_t)n * PP + p0 + pix) * 256 + ck * 8) = t.v;
    }
    #pragma unroll
    for (int it = 0; it < 4; ++it) {
        const int u = it * 256 + tid;
        const int pix = u & 15, ck = u >> 4;
        const int g = ck >> 3, c8 = (ck & 7) * 8;
        union { __hip_bfloat16 h8[8]; bf16x8 v; } t;
        #pragma unroll
        for (int j = 0; j < 8; ++j)
            t.h8[j] = (__hip_bfloat16)hs[(ck * 8 + j) * 17 + pix];
        *reinterpret_cast<bf16x8*>(
            xhT + ((size_t)(n * GG + g) * PP + p0 + pix) * 128 + 64 + c8) = t.v;
    }
}

// ---------------------------------------------------------------------------
// Kernel 1b: proj GEMM via MFMA. Chunk-major Wp addressing. grid 192 x 256.
// ---------------------------------------------------------------------------
__global__ __launch_bounds__(256) void proj_mfma_kernel(
    const __hip_bfloat16* __restrict__ xiT, const __hip_bfloat16* __restrict__ Wp,
    __hip_bfloat16* xhT)
{
    const int b = blockIdx.x;
    const int g = b & 7;
    const int j = b >> 3;
    const int n = j / 12;
    const int yt = j % 12;
    const int ng = n * GG + g;
    const int tid = threadIdx.x;
    const int w = tid >> 6, lane = tid & 63;
    const int col = lane & 15, quad = lane >> 4;
    const int y = yt * 4 + w;

    f32x4 acc[12];
    #pragma unroll
    for (int i = 0; i < 12; ++i) acc[i] = (f32x4){0.f, 0.f, 0.f, 0.f};

    const __hip_bfloat16* wgbase = Wp + (size_t)g * 24 * 2048 + col * 32 + quad * 8;

    for (int kk = 0; kk < 24; ++kk) {
        bf16x8 bfr[3];
        if (kk < 8) {
            const __hip_bfloat16* bp =
                xiT + ((size_t)n * PP + y * 48 + col) * 256 + kk * 32 + quad * 8;
            #pragma unroll
            for (int nf = 0; nf < 3; ++nf)
                bfr[nf] = ldb8(bp + (size_t)(nf * 16) * 256);
        } else {
            const int kh = kk - 8;
            const int gp = kh >> 1;
            const int c0 = (kh & 1) * 32;
            const __hip_bfloat16* bp =
                xhT + ((size_t)(n * GG + gp) * PP + y * 48 + col) * 128 + 64 + c0 + quad * 8;
            #pragma unroll
            for (int nf = 0; nf < 3; ++nf)
                bfr[nf] = ldb8(bp + (size_t)(nf * 16) * 128);
        }
        const __hip_bfloat16* wp = wgbase + kk * 2048;
        #pragma unroll
        for (int cf = 0; cf < 4; ++cf) {
            const bf16x8 af = ldb8(wp + cf * 512);
            #pragma unroll
            for (int nf = 0; nf < 3; ++nf)
                acc[cf * 3 + nf] = __builtin_amdgcn_mfma_f32_16x16x32_bf16(
                    af, bfr[nf], acc[cf * 3 + nf], 0, 0, 0);
        }
    }

    __hip_bfloat16* dst = xhT + (size_t)ng * PP * 128;
    #pragma unroll
    for (int cf = 0; cf < 4; ++cf)
        #pragma unroll
        for (int nf = 0; nf < 3; ++nf) {
            const int pix = y * 48 + nf * 16 + col;
            store4bf(dst + (size_t)pix * 128 + cf * 16 + quad * 4, acc[cf * 3 + nf]);
        }
}

// ---------------------------------------------------------------------------
// Kernel 2: fused q/k/v grouped 3x3 conv via MFMA (round-9 form: V output
// row-major with DPADV stride). grid 576 x 512.
// ---------------------------------------------------------------------------
__global__ __launch_bounds__(512) void conv_qkv_kernel(
    const __hip_bfloat16* __restrict__ xhT, const __hip_bfloat16* __restrict__ Wr,
    const float* __restrict__ tau,
    __hip_bfloat16* __restrict__ qT, __hip_bfloat16* __restrict__ kT,
    __hip_bfloat16* __restrict__ v)
{
    const int b = blockIdx.x;                // 0..575
    const int xcd = b & 7;
    const int j = b >> 3;
    const int s = xcd + 8 * (j / 12);
    const int yt = j % 12;
    const int t = s / 16;
    const int ng = s % 16;
    const int g = ng & 7;
    const int tid = threadIdx.x;
    const int w8 = tid >> 6, lane = tid & 63;
    const int yw = w8 & 3, chalf = w8 >> 2;
    const int cf0 = chalf * 2;
    const int col = lane & 15, quad = lane >> 4;
    const int y0 = yt * 4;
    const int yy = y0 + yw;
    const int ohw = (t == 0) ? 48 : 46;
    const int d0 = (t == 0) ? -1 : 0;
    const int soff = (t == 0) ? 1 : 0;       // stage column offset
    const bool wave_active = (yy < ohw);

    __shared__ __hip_bfloat16 st[8 * 300 * 8];   // [ck][lr*50+sc] x 8 bf16

    const __hip_bfloat16* slab = xhT + (size_t)ng * PP * 128;
    const __hip_bfloat16* wgbase =
        Wr + ((size_t)t * 8 + g) * 36 * 2048 + col * 32 + quad * 8;

    // zero the pad columns once (never overwritten by data stages)
    if (tid < 96) {
        const int ck = tid / 12, r2 = tid % 12;
        const int lr = r2 >> 1, side = r2 & 1;
        const int sc = side ? 49 : (soff ? 0 : 48);
        *reinterpret_cast<bf16x8*>(st + ((ck * 300) + lr * 50 + sc) * 8) =
            (bf16x8)(__bf16)0.f;
    }

    f32x4 acc[6];
    #pragma unroll
    for (int i = 0; i < 6; ++i) acc[i] = (f32x4){0.f, 0.f, 0.f, 0.f};

    for (int hc = 0; hc < 2; ++hc) {
        __syncthreads();
        #pragma unroll
        for (int it = 0; it < 5; ++it) {
            const int u = it * 512 + tid;
            if (u < 2304) {
                const int lr = u / 384;
                const int rem = u % 384;
                const int px = rem >> 3, ck = rem & 7;
                const int ry = y0 + d0 + lr;
                const int ryc = max(0, min(47, ry));
                bf16x8 vv = ldb8(slab + ((size_t)(ryc * 48 + px)) * 128 + hc * 64 + ck * 8);
                *reinterpret_cast<bf16x8*>(st + ((ck * 300) + lr * 50 + px + soff) * 8) =
                    (ry == ryc) ? vv : (bf16x8)(__bf16)0.f;
            }
        }
        __syncthreads();
        if (!wave_active) continue;

        #pragma unroll
        for (int ky = 0; ky < 3; ++ky) {
            const int lrk = (yw + ky) * 50;
            #pragma unroll
            for (int kx = 0; kx < 3; ++kx) {
                const int scb = col + kx;
                #pragma unroll
                for (int c32 = 0; c32 < 2; ++c32) {
                    bf16x8 bfr[3];
                    #pragma unroll
                    for (int nf = 0; nf < 3; ++nf)
                        bfr[nf] = *reinterpret_cast<const bf16x8*>(
                            st + (((c32 * 4 + quad) * 300) + lrk + nf * 16 + scb) * 8);
                    const __hip_bfloat16* wp =
                        wgbase + ((ky * 3 + kx) * 4 + hc * 2 + c32) * 2048;
                    if (t != 2) {
                        #pragma unroll
                        for (int cc = 0; cc < 2; ++cc) {
                            const bf16x8 af = ldb8(wp + (cf0 + cc) * 512);
                            #pragma unroll
                            for (int nf = 0; nf < 3; ++nf)
                                acc[cc * 3 + nf] = __builtin_amdgcn_mfma_f32_16x16x32_bf16(
                                    af, bfr[nf], acc[cc * 3 + nf], 0, 0, 0);
                        }
                    } else {
                        #pragma unroll
                        for (int cc = 0; cc < 2; ++cc) {
                            const bf16x8 af = ldb8(wp + (cf0 + cc) * 512);
                            #pragma unroll
                            for (int nf = 0; nf < 3; ++nf)
                                acc[cc * 3 + nf] = __builtin_amdgcn_mfma_f32_16x16x32_bf16(
                                    bfr[nf], af, acc[cc * 3 + nf], 0, 0, 0);
                        }
                    }
                }
            }
        }
    }

    if (!wave_active) return;
    if (t == 0) {
        const float ts = tau[g] * 1.44269504088896340736f;  // fold log2(e)
        __hip_bfloat16* dst = qT + (size_t)ng * PP * 64;
        #pragma unroll
        for (int cc = 0; cc < 2; ++cc)
            #pragma unroll
            for (int nf = 0; nf < 3; ++nf) {
                const int pix = yy * 48 + nf * 16 + col;
                store4bf(dst + (size_t)pix * 64 + (cf0 + cc) * 16 + quad * 4,
                         acc[cc * 3 + nf] * ts);
            }
    } else if (t == 1) {
        __hip_bfloat16* dst = kT + (size_t)ng * DD * 64;
        #pragma unroll
        for (int cc = 0; cc < 2; ++cc)
            #pragma unroll
            for (int nf = 0; nf < 3; ++nf) {
                const int x = nf * 16 + col;
                if (x < 46) {
                    const int pix = yy * 46 + x;
                    store4bf(dst + (size_t)pix * 64 + (cf0 + cc) * 16 + quad * 4,
                             acc[cc * 3 + nf]);
                }
            }
    } else {
        __hip_bfloat16* dst = v + (size_t)ng * 64 * DPADV;
        #pragma unroll
        for (int cc = 0; cc < 2; ++cc) {
            const int co = (cf0 + cc) * 16 + col;
            #pragma unroll
            for (int nf = 0; nf < 3; ++nf) {
                const int x4 = nf * 16 + quad * 4;
                #pragma unroll
                for (int r = 0; r < 4; ++r) {
                    if (x4 + r < 46)
                        dst[(size_t)co * DPADV + yy * 46 + x4 + r] =
                            (__hip_bfloat16)acc[cc * 3 + nf][r];
                }
            }
        }
    }
}

// ---------------------------------------------------------------------------
// Kernel 3: MFMA flash attention (round-9 two-q-tile form) + s_setprio
// around the MFMA clusters (T5: waves are at independent phases during the
// split-D sweep, the structure where setprio measured +4-7%).
// grid 1152 x 256.
// ---------------------------------------------------------------------------
__global__ __launch_bounds__(256) void attn_kernel(
    __hip_bfloat16* qa,                      // qT in (tau*log2e-scaled), aT out
    const __hip_bfloat16* __restrict__ kT,
    const __hip_bfloat16* __restrict__ vT)
{
    const int idx = blockIdx.x;              // 0..1151, idx&7 = group (XCD affinity)
    const int j3  = idx >> 3;                // 0..143
    const int sub = (j3 >= 72) ? 1 : 0;
    const int ng  = (idx & 7) + 8 * sub;
    const int qt  = j3 - 72 * sub;           // 0..71
    const int tid = threadIdx.x;
    const int w = tid >> 6, lane = tid & 63;
    const int col = lane & 15, quad = lane >> 4;
    const int qbase = qt * 32;

    // per-wave key-chunk: [it0, it1) full 32-key tiles; w==3 also does tail
    const int it0 = w * 17;
    const int it1 = (w < 3) ? (it0 + 17) : 66;

    __shared__ float lmS[3][2][64];
    __shared__ float llS[3][2][64];
    __shared__ float laccS[3][2][64][16];

    __hip_bfloat16* qrowA = qa + ((size_t)ng * PP + qbase + col) * CGR;
    __hip_bfloat16* qrowB = qrowA + 16 * CGR;
    const bf16x8 qfA0 = ldb8(qrowA + quad * 8);
    const bf16x8 qfA1 = ldb8(qrowA + 32 + quad * 8);
    const bf16x8 qfB0 = ldb8(qrowB + quad * 8);
    const bf16x8 qfB1 = ldb8(qrowB + 32 + quad * 8);

    const __hip_bfloat16* kbase = kT + (size_t)ng * DD * CGR;
    const __hip_bfloat16* vbase = vT + (size_t)ng * CGR * DPADV;
    const __hip_bfloat16* vrow[4];
    #pragma unroll
    for (int cf = 0; cf < 4; ++cf)
        vrow[cf] = vbase + (size_t)(cf * 16 + col) * DPADV;

    // permuted tile-local key for this lane's A-rows
    const int key0 = ((col >> 2) << 3) + (col & 3);
    const __hip_bfloat16* p0 = kbase + (size_t)(it0 * 32 + key0) * CGR + quad * 8;
    const __hip_bfloat16* p1 = p0 + 4 * CGR;

    f32x4 accA[4], accB[4];
    #pragma unroll
    for (int cf = 0; cf < 4; ++cf) {
        accA[cf] = (f32x4){0.f, 0.f, 0.f, 0.f};
        accB[cf] = (f32x4){0.f, 0.f, 0.f, 0.f};
    }
    float mA = -INFINITY, mB = -INFINITY;    // col-uniform running max (exp2 dom)
    float lA = 0.f, lB = 0.f;                // PER-LANE partial denominators
    const f32x4 zero = {0.f, 0.f, 0.f, 0.f};

    for (int it = it0; it < it1; ++it) {
        const int dbase = it * 32;
        const bf16x8 K0a = ldb8(p0), K0b = ldb8(p0 + 32);
        const bf16x8 K1a = ldb8(p1), K1b = ldb8(p1 + 32);
        p0 += 32 * CGR; p1 += 32 * CGR;

        __builtin_amdgcn_s_setprio(1);
        f32x4 SA0 = __builtin_amdgcn_mfma_f32_16x16x32_bf16(K0a, qfA0, zero, 0, 0, 0);
        SA0 = __builtin_amdgcn_mfma_f32_16x16x32_bf16(K0b, qfA1, SA0, 0, 0, 0);
        f32x4 SA1 = __builtin_amdgcn_mfma_f32_16x16x32_bf16(K1a, qfA0, zero, 0, 0, 0);
        SA1 = __builtin_amdgcn_mfma_f32_16x16x32_bf16(K1b, qfA1, SA1, 0, 0, 0);
        f32x4 SB0 = __builtin_amdgcn_mfma_f32_16x16x32_bf16(K0a, qfB0, zero, 0, 0, 0);
        SB0 = __builtin_amdgcn_mfma_f32_16x16x32_bf16(K0b, qfB1, SB0, 0, 0, 0);
        f32x4 SB1 = __builtin_amdgcn_mfma_f32_16x16x32_bf16(K1a, qfB0, zero, 0, 0, 0);
        SB1 = __builtin_amdgcn_mfma_f32_16x16x32_bf16(K1b, qfB1, SB1, 0, 0, 0);
        __builtin_amdgcn_s_setprio(0);

        // hoist V loads: independent of softmax, latency hides under exp chain
        const int da = dbase + quad * 8;
        const bf16x8 vf0 = ldb8(vrow[0] + da);
        const bf16x8 vf1 = ldb8(vrow[1] + da);
        const bf16x8 vf2 = ldb8(vrow[2] + da);
        const bf16x8 vf3 = ldb8(vrow[3] + da);

        const float lmAx = fmaxf(fmaxf(fmaxf(SA0[0], SA0[1]), fmaxf(SA0[2], SA0[3])),
                                 fmaxf(fmaxf(SA1[0], SA1[1]), fmaxf(SA1[2], SA1[3])));
        const float lmBx = fmaxf(fmaxf(fmaxf(SB0[0], SB0[1]), fmaxf(SB0[2], SB0[3])),
                                 fmaxf(fmaxf(SB1[0], SB1[1]), fmaxf(SB1[2], SB1[3])));

        if (__any((lmAx > mA + 8.f) || (lmBx > mB + 8.f))) {
            // rare path: full cross-lane max reduce + rescale
            float sA = lmAx;
            sA = fmaxf(sA, __shfl_xor(sA, 16, 64));
            sA = fmaxf(sA, __shfl_xor(sA, 32, 64));
            float sB = lmBx;
            sB = fmaxf(sB, __shfl_xor(sB, 16, 64));
            sB = fmaxf(sB, __shfl_xor(sB, 32, 64));
            const float mnA = fmaxf(mA, sA), mnB = fmaxf(mB, sB);
            const float aA = ex2(mA - mnA), aB = ex2(mB - mnB);
            lA *= aA; lB *= aB;
            #pragma unroll
            for (int cf = 0; cf < 4; ++cf) { accA[cf] *= aA; accB[cf] *= aB; }
            mA = mnA; mB = mnB;
        }

        float eA[8], eB[8];
        float lsA = 0.f, lsB = 0.f;
        #pragma unroll
        for (int r = 0; r < 4; ++r) {
            eA[r]     = ex2(SA0[r] - mA);
            eA[4 + r] = ex2(SA1[r] - mA);
            eB[r]     = ex2(SB0[r] - mB);
            eB[4 + r] = ex2(SB1[r] - mB);
            lsA += eA[r] + eA[4 + r];
            lsB += eB[r] + eB[4 + r];
        }
        lA += lsA; lB += lsB;

        bf16x8 ptA, ptB;
        #pragma unroll
        for (int jj = 0; jj < 8; ++jj) { ptA[jj] = (__bf16)eA[jj]; ptB[jj] = (__bf16)eB[jj]; }

        __builtin_amdgcn_s_setprio(1);
        accA[0] = __builtin_amdgcn_mfma_f32_16x16x32_bf16(vf0, ptA, accA[0], 0, 0, 0);
        accB[0] = __builtin_amdgcn_mfma_f32_16x16x32_bf16(vf0, ptB, accB[0], 0, 0, 0);
        accA[1] = __builtin_amdgcn_mfma_f32_16x16x32_bf16(vf1, ptA, accA[1], 0, 0, 0);
        accB[1] = __builtin_amdgcn_mfma_f32_16x16x32_bf16(vf1, ptB, accB[1], 0, 0, 0);
        accA[2] = __builtin_amdgcn_mfma_f32_16x16x32_bf16(vf2, ptA, accA[2], 0, 0, 0);
        accB[2] = __builtin_amdgcn_mfma_f32_16x16x32_bf16(vf2, ptB, accB[2], 0, 0, 0);
        accA[3] = __builtin_amdgcn_mfma_f32_16x16x32_bf16(vf3, ptA, accA[3], 0, 0, 0);
        accB[3] = __builtin_amdgcn_mfma_f32_16x16x32_bf16(vf3, ptB, accB[3], 0, 0, 0);
        __builtin_amdgcn_s_setprio(0);
    }

    // ---- masked tail tile (w==3 only): keys 2112..2143, valid < 2116 ----
    if (w == 3) {
        const int dbase = 66 * 32;
        const int kk0 = min(dbase + key0, DD - 1);
        const int kk1 = min(dbase + key0 + 4, DD - 1);
        const __hip_bfloat16* t0 = kbase + (size_t)kk0 * CGR + quad * 8;
        const __hip_bfloat16* t1 = kbase + (size_t)kk1 * CGR + quad * 8;
        const bf16x8 Ka = ldb8(t0), Kb = ldb8(t0 + 32);
        const bf16x8 Kc = ldb8(t1), Kd = ldb8(t1 + 32);

        f32x4 SA0 = __builtin_amdgcn_mfma_f32_16x16x32_bf16(Ka, qfA0, zero, 0, 0, 0);
        SA0 = __builtin_amdgcn_mfma_f32_16x16x32_bf16(Kb, qfA1, SA0, 0, 0, 0);
        f32x4 SA1 = __builtin_amdgcn_mfma_f32_16x16x32_bf16(Kc, qfA0, zero, 0, 0, 0);
        SA1 = __builtin_amdgcn_mfma_f32_16x16x32_bf16(Kd, qfA1, SA1, 0, 0, 0);
        f32x4 SB0 = __builtin_amdgcn_mfma_f32_16x16x32_bf16(Ka, qfB0, zero, 0, 0, 0);
        SB0 = __builtin_amdgcn_mfma_f32_16x16x32_bf16(Kb, qfB1, SB0, 0, 0, 0);
        f32x4 SB1 = __builtin_amdgcn_mfma_f32_16x16x32_bf16(Kc, qfB0, zero, 0, 0, 0);
        SB1 = __builtin_amdgcn_mfma_f32_16x16x32_bf16(Kd, qfB1, SB1, 0, 0, 0);

        float eA[8], eB[8];
        #pragma unroll
        for (int r = 0; r < 4; ++r) {
            const bool v0 = (dbase + quad * 8 + r     < DD);
            const bool v1 = (dbase + quad * 8 + 4 + r < DD);
            eA[r]     = v0 ? SA0[r] : -1e30f;
            eA[4 + r] = v1 ? SA1[r] : -1e30f;
            eB[r]     = v0 ? SB0[r] : -1e30f;
            eB[4 + r] = v1 ? SB1[r] : -1e30f;
        }
        float sA = fmaxf(fmaxf(fmaxf(eA[0], eA[1]), fmaxf(eA[2], eA[3])),
                         fmaxf(fmaxf(eA[4], eA[5]), fmaxf(eA[6], eA[7])));
        sA = fmaxf(sA, __shfl_xor(sA, 16, 64));
        sA = fmaxf(sA, __shfl_xor(sA, 32, 64));
        float sB = fmaxf(fmaxf(fmaxf(eB[0], eB[1]), fmaxf(eB[2], eB[3])),
                         fmaxf(fmaxf(eB[4], eB[5]), fmaxf(eB[6], eB[7])));
        sB = fmaxf(sB, __shfl_xor(sB, 16, 64));
        sB = fmaxf(sB, __shfl_xor(sB, 32, 64));
        const float mnA = fmaxf(mA, sA), mnB = fmaxf(mB, sB);
        const float aA = ex2(mA - mnA), aB = ex2(mB - mnB);
        float lsA = 0.f, lsB = 0.f;
        #pragma unroll
        for (int jj = 0; jj < 8; ++jj) {
            eA[jj] = ex2(eA[jj] - mnA); lsA += eA[jj];
            eB[jj] = ex2(eB[jj] - mnB); lsB += eB[jj];
        }
        lA = lA * aA + lsA;
        lB = lB * aB + lsB;
        mA = mnA; mB = mnB;

        bf16x8 ptA, ptB;
        #pragma unroll
        for (int jj = 0; jj < 8; ++jj) { ptA[jj] = (__bf16)eA[jj]; ptB[jj] = (__bf16)eB[jj]; }

        int da = dbase + quad * 8;
        if (da >= DD) da = 0;                // fully-masked quads: P==0
        #pragma unroll
        for (int cf = 0; cf < 4; ++cf) {
            accA[cf] *= aA; accB[cf] *= aB;
            const bf16x8 vf = ldb8(vrow[cf] + da);
            accA[cf] = __builtin_amdgcn_mfma_f32_16x16x32_bf16(vf, ptA, accA[cf], 0, 0, 0);
            accB[cf] = __builtin_amdgcn_mfma_f32_16x16x32_bf16(vf, ptB, accB[cf], 0, 0, 0);
        }
    }

    // ---- cross-wave merge of (m, l, acc) partials via LDS ----
    if (w != 0) {
        lmS[w - 1][0][lane] = mA; lmS[w - 1][1][lane] = mB;
        llS[w - 1][0][lane] = lA; llS[w - 1][1][lane] = lB;
        #pragma unroll
        for (int cf = 0; cf < 4; ++cf) {
            *reinterpret_cast<f32x4*>(&laccS[w - 1][0][lane][cf * 4]) = accA[cf];
            *reinterpret_cast<f32x4*>(&laccS[w - 1][1][lane][cf * 4]) = accB[cf];
        }
    }
    __syncthreads();
    if (w != 0) return;

    #pragma unroll
    for (int ww = 0; ww < 3; ++ww) {
        {
            const float mo = lmS[ww][0][lane];
            const float lo = llS[ww][0][lane];
            const float mn = fmaxf(mA, mo);
            const float a0 = ex2(mA - mn);
            const float a1 = ex2(mo - mn);
            lA = lA * a0 + lo * a1;
            #pragma unroll
            for (int cf = 0; cf < 4; ++cf) {
                const f32x4 o = *reinterpret_cast<const f32x4*>(&laccS[ww][0][lane][cf * 4]);
                accA[cf] = accA[cf] * a0 + o * a1;
            }
            mA = mn;
        }
        {
            const float mo = lmS[ww][1][lane];
            const float lo = llS[ww][1][lane];
            const float mn = fmaxf(mB, mo);
            const float a0 = ex2(mB - mn);
            const float a1 = ex2(mo - mn);
            lB = lB * a0 + lo * a1;
            #pragma unroll
            for (int cf = 0; cf < 4; ++cf) {
                const f32x4 o = *reinterpret_cast<const f32x4*>(&laccS[ww][1][lane][cf * 4]);
                accB[cf] = accB[cf] * a0 + o * a1;
            }
            mB = mn;
        }
    }

    // single cross-lane reduce of the per-lane partial denominators
    lA += __shfl_xor(lA, 16, 64);
    lA += __shfl_xor(lA, 32, 64);
    lB += __shfl_xor(lB, 16, 64);
    lB += __shfl_xor(lB, 32, 64);

    const float invA = 1.f / lA;
    const float invB = 1.f / lB;
    #pragma unroll
    for (int cf = 0; cf < 4; ++cf) {
        store4bf(qrowA + cf * 16 + quad * 4, accA[cf] * invA);
        store4bf(qrowB + cf * 16 + quad * 4, accB[cf] * invB);
    }
}

// ---------------------------------------------------------------------------
// Kernel 4: fused gates via MFMA + LSTM update (round-9 form).
// grid 768 x 512.
// ---------------------------------------------------------------------------
__global__ __launch_bounds__(512) void gates_kernel(
    const __hip_bfloat16* __restrict__ xhT, const __hip_bfloat16* __restrict__ aT,
    const float* __restrict__ c_in,
    const __hip_bfloat16* __restrict__ Wr, const __hip_bfloat16* __restrict__ Wa,
    const float* __restrict__ b_i, const float* __restrict__ b_f,
    const float* __restrict__ b_g, const float* __restrict__ b_o,
    float* __restrict__ h_out)
{
    const int b = blockIdx.x;                // 0..767
    const int xcd = b & 7;
    const int j = b >> 3;                    // 0..95
    const int ng = xcd + 8 * (j / 48);
    const int yy = j % 48;
    const int n = ng >> 3, g = ng & 7;
    const int tid = threadIdx.x;
    const int w8 = tid >> 6, lane = tid & 63;
    const int gate = w8 & 3, chalf = w8 >> 2;
    const int cf0 = chalf * 2;
    const int col = lane & 15, quad = lane >> 4;

    __shared__ char smem[38400];             // max(stage 38400, exchange 24576)
    __hip_bfloat16* st = (__hip_bfloat16*)smem;
    float* ex = (float*)smem;

    const __hip_bfloat16* slab = xhT + (size_t)ng * PP * 128;

    // zero pad columns (sc = 0 and 49)
    if (tid < 96) {
        const int ck = tid / 6, r2 = tid % 6;
        const int lr = r2 >> 1, side = r2 & 1;
        const int sc = side ? 49 : 0;
        *reinterpret_cast<bf16x8*>(st + ((ck * 150) + lr * 50 + sc) * 8) =
            (bf16x8)(__bf16)0.f;
    }
    // stage 3 rows x 48 px x 16 ck, zeroing OOB rows; data at sc = px+1
    #pragma unroll
    for (int it = 0; it < 5; ++it) {
        const int u = it * 512 + tid;
        if (u < 2304) {
            const int lr = u / 768;
            const int rem = u % 768;
            const int px = rem >> 4, ck = rem & 15;
            const int ry = yy - 1 + lr;
            const int ryc = max(0, min(47, ry));
            bf16x8 vv = ldb8(slab + ((size_t)(ryc * 48 + px)) * 128 + ck * 8);
            *reinterpret_cast<bf16x8*>(st + ((ck * 150) + lr * 50 + px + 1) * 8) =
                (ry == ryc) ? vv : (bf16x8)(__bf16)0.f;
        }
    }
    __syncthreads();

    f32x4 acc[6];
    #pragma unroll
    for (int i = 0; i < 6; ++i) acc[i] = (f32x4){0.f, 0.f, 0.f, 0.f};

    const __hip_bfloat16* wgbase =
        Wr + ((size_t)(3 + gate) * 8 + g) * 36 * 2048 + col * 32 + quad * 8;

    #pragma unroll
    for (int ky = 0; ky < 3; ++ky) {
        const int lrk = ky * 50;
        #pragma unroll
        for (int kx = 0; kx < 3; ++kx) {
            const int scb = col + kx;
            #pragma unroll
            for (int c32 = 0; c32 < 4; ++c32) {
                bf16x8 bfr[3];
                #pragma unroll
                for (int nf = 0; nf < 3; ++nf)
                    bfr[nf] = *reinterpret_cast<const bf16x8*>(
                        st + (((c32 * 4 + quad) * 150) + lrk + nf * 16 + scb) * 8);
                const __hip_bfloat16* wp =
                    wgbase + ((ky * 3 + kx) * 4 + c32) * 2048;
                #pragma unroll
                for (int cc = 0; cc < 2; ++cc) {
                    const bf16x8 af = ldb8(wp + (cf0 + cc) * 512);
                    #pragma unroll
                    for (int nf = 0; nf < 3; ++nf)
                        acc[cc * 3 + nf] = __builtin_amdgcn_mfma_f32_16x16x32_bf16(
                            af, bfr[nf], acc[cc * 3 + nf], 0, 0, 0);
                }
            }
        }
    }

    {
        const __hip_bfloat16* wa =
            Wa + (size_t)gate * 32768 + ((size_t)(g * 64) + col) * 64;
        const __hip_bfloat16* ab = aT + ((size_t)ng * PP + yy * 48) * 64;
        #pragma unroll
        for (int c32 = 0; c32 < 2; ++c32) {
            bf16x8 bfr[3];
            #pragma unroll
            for (int nf = 0; nf < 3; ++nf)
                bfr[nf] = ldb8(ab + (size_t)(nf * 16 + col) * 64 + c32 * 32 + quad * 8);
            #pragma unroll
            for (int cc = 0; cc < 2; ++cc) {
                const bf16x8 af = ldb8(wa + (size_t)((cf0 + cc) * 16) * 64 + c32 * 32 + quad * 8);
                #pragma unroll
                for (int nf = 0; nf < 3; ++nf)
                    acc[cc * 3 + nf] = __builtin_amdgcn_mfma_f32_16x16x32_bf16(
                        af, bfr[nf], acc[cc * 3 + nf], 0, 0, 0);
            }
        }
    }

    const float* bias = (gate == 0) ? b_i : (gate == 1) ? b_f : (gate == 2) ? b_g : b_o;
    #pragma unroll
    for (int cc = 0; cc < 2; ++cc) {
        #pragma unroll
        for (int r = 0; r < 4; ++r) {
            const float bv = bias[g * 64 + (cf0 + cc) * 16 + quad * 4 + r];
            #pragma unroll
            for (int nf = 0; nf < 3; ++nf)
                acc[cc * 3 + nf][r] += bv;
        }
    }

    for (int hh = 0; hh < 2; ++hh) {
        __syncthreads();
        if (chalf == hh) {
            #pragma unroll
            for (int cc = 0; cc < 2; ++cc)
                #pragma unroll
                for (int nf = 0; nf < 3; ++nf)
                    #pragma unroll
                    for (int r = 0; r < 4; ++r)
                        ex[(size_t)gate * 1536 + (cc * 16 + quad * 4 + r) * 48 + nf * 16 + col] =
                            acc[cc * 3 + nf][r];
        }
        __syncthreads();
        #pragma unroll
        for (int k2 = 0; k2 < 3; ++k2) {
            const int idx = k2 * 512 + tid;
            const int co32 = idx / 48, px = idx % 48;
            const float iv = ex[0 * 1536 + co32 * 48 + px];
            const float fv = ex[1 * 1536 + co32 * 48 + px];
            const float gv = ex[2 * 1536 + co32 * 48 + px];
            const float ov = ex[3 * 1536 + co32 * 48 + px];
            const int c = g * 64 + hh * 32 + co32;
            const size_t off = ((size_t)n * CC + c) * PP + yy * 48 + px;
            const float ig = sig_fast(iv);
            const float fg = sig_fast(fv);
            const float gg = tanh_fast(gv);
            const float og = sig_fast(ov);
            const float cn = fg * c_in[off] + ig * gg;
            h_out[off] = og * tanh_fast(cn);
        }
    }
}

// ---------------------------------------------------------------------------
extern "C" void kernel_launch(void* const* d_in, const int* in_sizes, int n_in,
                              void* d_out, int out_size, void* d_ws, size_t ws_size,
                              hipStream_t stream)
{
    const float* x_in = (const float*)d_in[0];
    const float* h    = (const float*)d_in[1];
    const float* c    = (const float*)d_in[2];
    const float* tau  = (const float*)d_in[3];
    const float* W_x  = (const float*)d_in[4];
    const float* W_ig = (const float*)d_in[5];
    const float* W_q  = (const float*)d_in[6];
    const float* W_k  = (const float*)d_in[7];
    const float* W_v  = (const float*)d_in[8];
    const float* Wi_a = (const float*)d_in[9];
    const float* Wi_x = (const float*)d_in[10];
    const float* b_i  = (const float*)d_in[11];
    const float* Wf_a = (const float*)d_in[12];
    const float* Wf_x = (const float*)d_in[13];
    const float* b_f  = (const float*)d_in[14];
    const float* Wg_a = (const float*)d_in[15];
    const float* Wg_x = (const float*)d_in[16];
    const float* b_g  = (const float*)d_in[17];
    const float* Wo_a = (const float*)d_in[18];
    const float* Wo_x = (const float*)d_in[19];
    const float* b_o  = (const float*)d_in[20];
    float* out = (float*)d_out;

    // Workspace (bf16 elements), total 34,496,512 B (~32.9 MB)
    __hip_bfloat16* wsb = (__hip_bfloat16*)d_ws;
    __hip_bfloat16* xhT = wsb;                        // 4,718,592
    __hip_bfloat16* qa  = xhT + (size_t)4718592;      // 2,359,296
    __hip_bfloat16* kT  = qa  + (size_t)2359296;      // 2,166,784
    __hip_bfloat16* vv  = kT  + (size_t)2166784;      // 2,170,880
    __hip_bfloat16* Wr  = vv  + (size_t)2170880;      // 4,128,768
    __hip_bfloat16* Wa  = Wr  + (size_t)4128768;      //   131,072
    __hip_bfloat16* Wp  = Wa  + (size_t)131072;       //   393,216
    __hip_bfloat16* xiT = Wp  + (size_t)393216;       // 1,179,648

    dim3 blk(256);
    dim3 blk8(512);
    prep_kernel<<<dim3(18176), blk, 0, stream>>>(
        W_q, W_k, W_v, Wi_x, Wf_x, Wg_x, Wo_x, Wi_a, Wf_a, Wg_a, Wo_a,
        W_x, W_ig, Wr, Wa, Wp);
    xpose_kernel<<<dim3(144, NB), blk, 0, stream>>>(x_in, h, xiT, xhT);
    proj_mfma_kernel<<<dim3(192), blk, 0, stream>>>(xiT, Wp, xhT);
    conv_qkv_kernel<<<dim3(576), blk8, 0, stream>>>(xhT, Wr, tau, qa, kT, vv);
    attn_kernel<<<dim3(1152), blk, 0, stream>>>(qa, kT, vv);
    gates_kernel<<<dim3(768), blk8, 0, stream>>>(
        xhT, qa, c, Wr, Wa, b_i, b_f, b_g, b_o, out);
}

// Round 14
// 283.820 us; speedup vs baseline: 1.0420x; 1.0072x over previous
//
#include <hip/hip_runtime.h>
#include <hip/hip_bf16.h>
#include <math.h>

// Problem constants
#define NB   2
#define CIN  256
#define CC   512
#define GG   8
#define CGR  64
#define HH   48
#define WW   48
#define PP   (HH*WW)        // 2304
#define HD   46
#define WD   46
#define DD   (HD*WD)        // 2116
#define DPADV 2120          // v row stride (16B-aligned rows)
#define WRT  589824         // 512*9*128 = 8*36*2048, per-tensor reordered weight stride

typedef __bf16 bf16x8 __attribute__((ext_vector_type(8)));
typedef float  f32x4  __attribute__((ext_vector_type(4)));

__device__ __forceinline__ bf16x8 ldb8(const __hip_bfloat16* p) {
    return *reinterpret_cast<const bf16x8*>(p);
}
__device__ __forceinline__ void store4bf(__hip_bfloat16* p, f32x4 v) {
    union { __hip_bfloat16 h[4]; uint2 u; } t;
    #pragma unroll
    for (int r = 0; r < 4; ++r) t.h[r] = (__hip_bfloat16)v[r];
    *reinterpret_cast<uint2*>(p) = t.u;
}
__device__ __forceinline__ float ex2(float x) {
    return __builtin_amdgcn_exp2f(x);
}
// sigmoid(x) = 1/(1+exp(-x)); exp via exp2, fast rcp (exact at +-inf limits)
__device__ __forceinline__ float sig_fast(float x) {
    return __builtin_amdgcn_rcpf(1.f + ex2(-1.44269504088896f * x));
}
// tanh(x) = 1 - 2/(exp(2x)+1); exact at +-inf limits
__device__ __forceinline__ float tanh_fast(float x) {
    return 1.f - 2.f * __builtin_amdgcn_rcpf(ex2(2.88539008177793f * x) + 1.f);
}

// ---------------------------------------------------------------------------
// Kernel 0: weight prep (chunk-major layout).
//   Wr[t][g][chunk 36][och 64][k 32],  chunk = tap*4 + ci/32, k = ci%32
//   Wp[g][chunk 24][och 64][k 32],     chunk = ci/32 (768 ci)
// ---------------------------------------------------------------------------
__global__ __launch_bounds__(256) void prep_kernel(
    const float* __restrict__ Wq, const float* __restrict__ Wk,
    const float* __restrict__ Wv, const float* __restrict__ Wix,
    const float* __restrict__ Wfx, const float* __restrict__ Wgx,
    const float* __restrict__ Wox, const float* __restrict__ Wia,
    const float* __restrict__ Wfa, const float* __restrict__ Wga,
    const float* __restrict__ Woa, const float* __restrict__ Wx,
    const float* __restrict__ Wig,
    __hip_bfloat16* __restrict__ Wr, __hip_bfloat16* __restrict__ Wa,
    __hip_bfloat16* __restrict__ Wp)
{
    const int i = blockIdx.x * 256 + threadIdx.x;
    const int N1 = 7 * WRT;
    const int N2 = N1 + 4 * 32768;
    if (i < N1) {
        const int t = i / WRT, r = i % WRT;
        const int g = r / 73728, r2 = r % 73728;
        const int chunk = r2 / 2048, r3 = r2 % 2048;
        const int och = r3 / 32, k = r3 % 32;
        const int tap = chunk >> 2;
        const int ci = (chunk & 3) * 32 + k;
        const int co = g * 64 + och;
        const float* src;
        switch (t) {
            case 0: src = Wq;  break;  case 1: src = Wk;  break;
            case 2: src = Wv;  break;  case 3: src = Wix; break;
            case 4: src = Wfx; break;  case 5: src = Wgx; break;
            default: src = Wox;
        }
        Wr[i] = (__hip_bfloat16)src[(size_t)co * 1152 + ci * 9 + tap];
    } else if (i < N2) {
        const int j = i - N1;
        const int t = j / 32768, r = j % 32768;
        const float* src = (t == 0) ? Wia : (t == 1) ? Wfa : (t == 2) ? Wga : Woa;
        Wa[j] = (__hip_bfloat16)src[r];
    } else {
        const int j = i - N2;                // 0..393215
        const int g = j / 49152, r = j % 49152;
        const int chunk = r / 2048, r3 = r % 2048;
        const int och = r3 / 32, k = r3 % 32;
        const int c = g * 64 + och;
        const int ci = chunk * 32 + k;
        Wp[j] = (__hip_bfloat16)((ci < 256) ? Wx[(size_t)c * 256 + ci]
                                            : Wig[(size_t)c * 512 + (ci - 256)]);
    }
}

// ---------------------------------------------------------------------------
// Kernel 1a: transpose/convert (unchanged).
// ---------------------------------------------------------------------------
__global__ __launch_bounds__(256) void xpose_kernel(
    const float* __restrict__ x_in, const float* __restrict__ h,
    __hip_bfloat16* __restrict__ xiT, __hip_bfloat16* __restrict__ xhT)
{
    const int pt = blockIdx.x;
    const int n  = blockIdx.y;
    const int p0 = pt * 16;
    const int tid = threadIdx.x;

    __shared__ float xs[CIN * 17];
    __shared__ float hs[CC * 17];

    const float* xb = x_in + (size_t)n * CIN * PP;
    const float* hb = h + (size_t)n * CC * PP;
    #pragma unroll
    for (int k = 0; k < 16; ++k) {
        const int idx = k * 256 + tid;
        xs[(idx >> 4) * 17 + (idx & 15)] = xb[(size_t)(idx >> 4) * PP + p0 + (idx & 15)];
    }
    #pragma unroll
    for (int k = 0; k < 32; ++k) {
        const int idx = k * 256 + tid;
        hs[(idx >> 4) * 17 + (idx & 15)] = hb[(size_t)(idx >> 4) * PP + p0 + (idx & 15)];
    }
    __syncthreads();

    #pragma unroll
    for (int it = 0; it < 2; ++it) {
        const int u = it * 256 + tid;
        const int pix = u & 15, ck = u >> 4;
        union { __hip_bfloat16 h8[8]; bf16x8 v; } t;
        #pragma unroll
        for (int j = 0; j < 8; ++j)
            t.h8[j] = (__hip_bfloat16)xs[(ck * 8 + j) * 17 + pix];
        *reinterpret_cast<bf16x8*>(
            xiT + ((size_t)n * PP + p0 + pix) * 256 + ck * 8) = t.v;
    }
    #pragma unroll
    for (int it = 0; it < 4; ++it) {
        const int u = it * 256 + tid;
        const int pix = u & 15, ck = u >> 4;
        const int g = ck >> 3, c8 = (ck & 7) * 8;
        union { __hip_bfloat16 h8[8]; bf16x8 v; } t;
        #pragma unroll
        for (int j = 0; j < 8; ++j)
            t.h8[j] = (__hip_bfloat16)hs[(ck * 8 + j) * 17 + pix];
        *reinterpret_cast<bf16x8*>(
            xhT + ((size_t)(n * GG + g) * PP + p0 + pix) * 128 + 64 + c8) = t.v;
    }
}

// ---------------------------------------------------------------------------
// Kernel 1b: proj GEMM via MFMA. Chunk-major Wp addressing. grid 192 x 256.
// ---------------------------------------------------------------------------
__global__ __launch_bounds__(256) void proj_mfma_kernel(
    const __hip_bfloat16* __restrict__ xiT, const __hip_bfloat16* __restrict__ Wp,
    __hip_bfloat16* xhT)
{
    const int b = blockIdx.x;
    const int g = b & 7;
    const int j = b >> 3;
    const int n = j / 12;
    const int yt = j % 12;
    const int ng = n * GG + g;
    const int tid = threadIdx.x;
    const int w = tid >> 6, lane = tid & 63;
    const int col = lane & 15, quad = lane >> 4;
    const int y = yt * 4 + w;

    f32x4 acc[12];
    #pragma unroll
    for (int i = 0; i < 12; ++i) acc[i] = (f32x4){0.f, 0.f, 0.f, 0.f};

    const __hip_bfloat16* wgbase = Wp + (size_t)g * 24 * 2048 + col * 32 + quad * 8;

    for (int kk = 0; kk < 24; ++kk) {
        bf16x8 bfr[3];
        if (kk < 8) {
            const __hip_bfloat16* bp =
                xiT + ((size_t)n * PP + y * 48 + col) * 256 + kk * 32 + quad * 8;
            #pragma unroll
            for (int nf = 0; nf < 3; ++nf)
                bfr[nf] = ldb8(bp + (size_t)(nf * 16) * 256);
        } else {
            const int kh = kk - 8;
            const int gp = kh >> 1;
            const int c0 = (kh & 1) * 32;
            const __hip_bfloat16* bp =
                xhT + ((size_t)(n * GG + gp) * PP + y * 48 + col) * 128 + 64 + c0 + quad * 8;
            #pragma unroll
            for (int nf = 0; nf < 3; ++nf)
                bfr[nf] = ldb8(bp + (size_t)(nf * 16) * 128);
        }
        const __hip_bfloat16* wp = wgbase + kk * 2048;
        #pragma unroll
        for (int cf = 0; cf < 4; ++cf) {
            const bf16x8 af = ldb8(wp + cf * 512);
            #pragma unroll
            for (int nf = 0; nf < 3; ++nf)
                acc[cf * 3 + nf] = __builtin_amdgcn_mfma_f32_16x16x32_bf16(
                    af, bfr[nf], acc[cf * 3 + nf], 0, 0, 0);
        }
    }

    __hip_bfloat16* dst = xhT + (size_t)ng * PP * 128;
    #pragma unroll
    for (int cf = 0; cf < 4; ++cf)
        #pragma unroll
        for (int nf = 0; nf < 3; ++nf) {
            const int pix = y * 48 + nf * 16 + col;
            store4bf(dst + (size_t)pix * 128 + cf * 16 + quad * 4, acc[cf * 3 + nf]);
        }
}

// ---------------------------------------------------------------------------
// Kernel 2: fused q/k/v grouped 3x3 conv via MFMA (round-9 form: V output
// row-major with DPADV stride). grid 576 x 512.
// ---------------------------------------------------------------------------
__global__ __launch_bounds__(512) void conv_qkv_kernel(
    const __hip_bfloat16* __restrict__ xhT, const __hip_bfloat16* __restrict__ Wr,
    const float* __restrict__ tau,
    __hip_bfloat16* __restrict__ qT, __hip_bfloat16* __restrict__ kT,
    __hip_bfloat16* __restrict__ v)
{
    const int b = blockIdx.x;                // 0..575
    const int xcd = b & 7;
    const int j = b >> 3;
    const int s = xcd + 8 * (j / 12);
    const int yt = j % 12;
    const int t = s / 16;
    const int ng = s % 16;
    const int g = ng & 7;
    const int tid = threadIdx.x;
    const int w8 = tid >> 6, lane = tid & 63;
    const int yw = w8 & 3, chalf = w8 >> 2;
    const int cf0 = chalf * 2;
    const int col = lane & 15, quad = lane >> 4;
    const int y0 = yt * 4;
    const int yy = y0 + yw;
    const int ohw = (t == 0) ? 48 : 46;
    const int d0 = (t == 0) ? -1 : 0;
    const int soff = (t == 0) ? 1 : 0;       // stage column offset
    const bool wave_active = (yy < ohw);

    __shared__ __hip_bfloat16 st[8 * 300 * 8];   // [ck][lr*50+sc] x 8 bf16

    const __hip_bfloat16* slab = xhT + (size_t)ng * PP * 128;
    const __hip_bfloat16* wgbase =
        Wr + ((size_t)t * 8 + g) * 36 * 2048 + col * 32 + quad * 8;

    // zero the pad columns once (never overwritten by data stages)
    if (tid < 96) {
        const int ck = tid / 12, r2 = tid % 12;
        const int lr = r2 >> 1, side = r2 & 1;
        const int sc = side ? 49 : (soff ? 0 : 48);
        *reinterpret_cast<bf16x8*>(st + ((ck * 300) + lr * 50 + sc) * 8) =
            (bf16x8)(__bf16)0.f;
    }

    f32x4 acc[6];
    #pragma unroll
    for (int i = 0; i < 6; ++i) acc[i] = (f32x4){0.f, 0.f, 0.f, 0.f};

    for (int hc = 0; hc < 2; ++hc) {
        __syncthreads();
        #pragma unroll
        for (int it = 0; it < 5; ++it) {
            const int u = it * 512 + tid;
            if (u < 2304) {
                const int lr = u / 384;
                const int rem = u % 384;
                const int px = rem >> 3, ck = rem & 7;
                const int ry = y0 + d0 + lr;
                const int ryc = max(0, min(47, ry));
                bf16x8 vv = ldb8(slab + ((size_t)(ryc * 48 + px)) * 128 + hc * 64 + ck * 8);
                *reinterpret_cast<bf16x8*>(st + ((ck * 300) + lr * 50 + px + soff) * 8) =
                    (ry == ryc) ? vv : (bf16x8)(__bf16)0.f;
            }
        }
        __syncthreads();
        if (!wave_active) continue;

        #pragma unroll
        for (int ky = 0; ky < 3; ++ky) {
            const int lrk = (yw + ky) * 50;
            #pragma unroll
            for (int kx = 0; kx < 3; ++kx) {
                const int scb = col + kx;
                #pragma unroll
                for (int c32 = 0; c32 < 2; ++c32) {
                    bf16x8 bfr[3];
                    #pragma unroll
                    for (int nf = 0; nf < 3; ++nf)
                        bfr[nf] = *reinterpret_cast<const bf16x8*>(
                            st + (((c32 * 4 + quad) * 300) + lrk + nf * 16 + scb) * 8);
                    const __hip_bfloat16* wp =
                        wgbase + ((ky * 3 + kx) * 4 + hc * 2 + c32) * 2048;
                    if (t != 2) {
                        #pragma unroll
                        for (int cc = 0; cc < 2; ++cc) {
                            const bf16x8 af = ldb8(wp + (cf0 + cc) * 512);
                            #pragma unroll
                            for (int nf = 0; nf < 3; ++nf)
                                acc[cc * 3 + nf] = __builtin_amdgcn_mfma_f32_16x16x32_bf16(
                                    af, bfr[nf], acc[cc * 3 + nf], 0, 0, 0);
                        }
                    } else {
                        #pragma unroll
                        for (int cc = 0; cc < 2; ++cc) {
                            const bf16x8 af = ldb8(wp + (cf0 + cc) * 512);
                            #pragma unroll
                            for (int nf = 0; nf < 3; ++nf)
                                acc[cc * 3 + nf] = __builtin_amdgcn_mfma_f32_16x16x32_bf16(
                                    bfr[nf], af, acc[cc * 3 + nf], 0, 0, 0);
                        }
                    }
                }
            }
        }
    }

    if (!wave_active) return;
    if (t == 0) {
        const float ts = tau[g] * 1.44269504088896340736f;  // fold log2(e)
        __hip_bfloat16* dst = qT + (size_t)ng * PP * 64;
        #pragma unroll
        for (int cc = 0; cc < 2; ++cc)
            #pragma unroll
            for (int nf = 0; nf < 3; ++nf) {
                const int pix = yy * 48 + nf * 16 + col;
                store4bf(dst + (size_t)pix * 64 + (cf0 + cc) * 16 + quad * 4,
                         acc[cc * 3 + nf] * ts);
            }
    } else if (t == 1) {
        __hip_bfloat16* dst = kT + (size_t)ng * DD * 64;
        #pragma unroll
        for (int cc = 0; cc < 2; ++cc)
            #pragma unroll
            for (int nf = 0; nf < 3; ++nf) {
                const int x = nf * 16 + col;
                if (x < 46) {
                    const int pix = yy * 46 + x;
                    store4bf(dst + (size_t)pix * 64 + (cf0 + cc) * 16 + quad * 4,
                             acc[cc * 3 + nf]);
                }
            }
    } else {
        __hip_bfloat16* dst = v + (size_t)ng * 64 * DPADV;
        #pragma unroll
        for (int cc = 0; cc < 2; ++cc) {
            const int co = (cf0 + cc) * 16 + col;
            #pragma unroll
            for (int nf = 0; nf < 3; ++nf) {
                const int x4 = nf * 16 + quad * 4;
                #pragma unroll
                for (int r = 0; r < 4; ++r) {
                    if (x4 + r < 46)
                        dst[(size_t)co * DPADV + yy * 46 + x4 + r] =
                            (__hip_bfloat16)acc[cc * 3 + nf][r];
                }
            }
        }
    }
}

// ---------------------------------------------------------------------------
// Kernel 3: MFMA flash attention (round-9 two-q-tile form, no setprio —
// measured -4us vs with-setprio in R13). grid 1152 x 256.
// ---------------------------------------------------------------------------
__global__ __launch_bounds__(256) void attn_kernel(
    __hip_bfloat16* qa,                      // qT in (tau*log2e-scaled), aT out
    const __hip_bfloat16* __restrict__ kT,
    const __hip_bfloat16* __restrict__ vT)
{
    const int idx = blockIdx.x;              // 0..1151, idx&7 = group (XCD affinity)
    const int j3  = idx >> 3;                // 0..143
    const int sub = (j3 >= 72) ? 1 : 0;
    const int ng  = (idx & 7) + 8 * sub;
    const int qt  = j3 - 72 * sub;           // 0..71
    const int tid = threadIdx.x;
    const int w = tid >> 6, lane = tid & 63;
    const int col = lane & 15, quad = lane >> 4;
    const int qbase = qt * 32;

    // per-wave key-chunk: [it0, it1) full 32-key tiles; w==3 also does tail
    const int it0 = w * 17;
    const int it1 = (w < 3) ? (it0 + 17) : 66;

    __shared__ float lmS[3][2][64];
    __shared__ float llS[3][2][64];
    __shared__ float laccS[3][2][64][16];

    __hip_bfloat16* qrowA = qa + ((size_t)ng * PP + qbase + col) * CGR;
    __hip_bfloat16* qrowB = qrowA + 16 * CGR;
    const bf16x8 qfA0 = ldb8(qrowA + quad * 8);
    const bf16x8 qfA1 = ldb8(qrowA + 32 + quad * 8);
    const bf16x8 qfB0 = ldb8(qrowB + quad * 8);
    const bf16x8 qfB1 = ldb8(qrowB + 32 + quad * 8);

    const __hip_bfloat16* kbase = kT + (size_t)ng * DD * CGR;
    const __hip_bfloat16* vbase = vT + (size_t)ng * CGR * DPADV;
    const __hip_bfloat16* vrow[4];
    #pragma unroll
    for (int cf = 0; cf < 4; ++cf)
        vrow[cf] = vbase + (size_t)(cf * 16 + col) * DPADV;

    // permuted tile-local key for this lane's A-rows
    const int key0 = ((col >> 2) << 3) + (col & 3);
    const __hip_bfloat16* p0 = kbase + (size_t)(it0 * 32 + key0) * CGR + quad * 8;
    const __hip_bfloat16* p1 = p0 + 4 * CGR;

    f32x4 accA[4], accB[4];
    #pragma unroll
    for (int cf = 0; cf < 4; ++cf) {
        accA[cf] = (f32x4){0.f, 0.f, 0.f, 0.f};
        accB[cf] = (f32x4){0.f, 0.f, 0.f, 0.f};
    }
    float mA = -INFINITY, mB = -INFINITY;    // col-uniform running max (exp2 dom)
    float lA = 0.f, lB = 0.f;                // PER-LANE partial denominators
    const f32x4 zero = {0.f, 0.f, 0.f, 0.f};

    for (int it = it0; it < it1; ++it) {
        const int dbase = it * 32;
        const bf16x8 K0a = ldb8(p0), K0b = ldb8(p0 + 32);
        const bf16x8 K1a = ldb8(p1), K1b = ldb8(p1 + 32);
        p0 += 32 * CGR; p1 += 32 * CGR;

        f32x4 SA0 = __builtin_amdgcn_mfma_f32_16x16x32_bf16(K0a, qfA0, zero, 0, 0, 0);
        SA0 = __builtin_amdgcn_mfma_f32_16x16x32_bf16(K0b, qfA1, SA0, 0, 0, 0);
        f32x4 SA1 = __builtin_amdgcn_mfma_f32_16x16x32_bf16(K1a, qfA0, zero, 0, 0, 0);
        SA1 = __builtin_amdgcn_mfma_f32_16x16x32_bf16(K1b, qfA1, SA1, 0, 0, 0);
        f32x4 SB0 = __builtin_amdgcn_mfma_f32_16x16x32_bf16(K0a, qfB0, zero, 0, 0, 0);
        SB0 = __builtin_amdgcn_mfma_f32_16x16x32_bf16(K0b, qfB1, SB0, 0, 0, 0);
        f32x4 SB1 = __builtin_amdgcn_mfma_f32_16x16x32_bf16(K1a, qfB0, zero, 0, 0, 0);
        SB1 = __builtin_amdgcn_mfma_f32_16x16x32_bf16(K1b, qfB1, SB1, 0, 0, 0);

        // hoist V loads: independent of softmax, latency hides under exp chain
        const int da = dbase + quad * 8;
        const bf16x8 vf0 = ldb8(vrow[0] + da);
        const bf16x8 vf1 = ldb8(vrow[1] + da);
        const bf16x8 vf2 = ldb8(vrow[2] + da);
        const bf16x8 vf3 = ldb8(vrow[3] + da);

        const float lmAx = fmaxf(fmaxf(fmaxf(SA0[0], SA0[1]), fmaxf(SA0[2], SA0[3])),
                                 fmaxf(fmaxf(SA1[0], SA1[1]), fmaxf(SA1[2], SA1[3])));
        const float lmBx = fmaxf(fmaxf(fmaxf(SB0[0], SB0[1]), fmaxf(SB0[2], SB0[3])),
                                 fmaxf(fmaxf(SB1[0], SB1[1]), fmaxf(SB1[2], SB1[3])));

        if (__any((lmAx > mA + 8.f) || (lmBx > mB + 8.f))) {
            // rare path: full cross-lane max reduce + rescale
            float sA = lmAx;
            sA = fmaxf(sA, __shfl_xor(sA, 16, 64));
            sA = fmaxf(sA, __shfl_xor(sA, 32, 64));
            float sB = lmBx;
            sB = fmaxf(sB, __shfl_xor(sB, 16, 64));
            sB = fmaxf(sB, __shfl_xor(sB, 32, 64));
            const float mnA = fmaxf(mA, sA), mnB = fmaxf(mB, sB);
            const float aA = ex2(mA - mnA), aB = ex2(mB - mnB);
            lA *= aA; lB *= aB;
            #pragma unroll
            for (int cf = 0; cf < 4; ++cf) { accA[cf] *= aA; accB[cf] *= aB; }
            mA = mnA; mB = mnB;
        }

        float eA[8], eB[8];
        float lsA = 0.f, lsB = 0.f;
        #pragma unroll
        for (int r = 0; r < 4; ++r) {
            eA[r]     = ex2(SA0[r] - mA);
            eA[4 + r] = ex2(SA1[r] - mA);
            eB[r]     = ex2(SB0[r] - mB);
            eB[4 + r] = ex2(SB1[r] - mB);
            lsA += eA[r] + eA[4 + r];
            lsB += eB[r] + eB[4 + r];
        }
        lA += lsA; lB += lsB;

        bf16x8 ptA, ptB;
        #pragma unroll
        for (int jj = 0; jj < 8; ++jj) { ptA[jj] = (__bf16)eA[jj]; ptB[jj] = (__bf16)eB[jj]; }

        accA[0] = __builtin_amdgcn_mfma_f32_16x16x32_bf16(vf0, ptA, accA[0], 0, 0, 0);
        accB[0] = __builtin_amdgcn_mfma_f32_16x16x32_bf16(vf0, ptB, accB[0], 0, 0, 0);
        accA[1] = __builtin_amdgcn_mfma_f32_16x16x32_bf16(vf1, ptA, accA[1], 0, 0, 0);
        accB[1] = __builtin_amdgcn_mfma_f32_16x16x32_bf16(vf1, ptB, accB[1], 0, 0, 0);
        accA[2] = __builtin_amdgcn_mfma_f32_16x16x32_bf16(vf2, ptA, accA[2], 0, 0, 0);
        accB[2] = __builtin_amdgcn_mfma_f32_16x16x32_bf16(vf2, ptB, accB[2], 0, 0, 0);
        accA[3] = __builtin_amdgcn_mfma_f32_16x16x32_bf16(vf3, ptA, accA[3], 0, 0, 0);
        accB[3] = __builtin_amdgcn_mfma_f32_16x16x32_bf16(vf3, ptB, accB[3], 0, 0, 0);
    }

    // ---- masked tail tile (w==3 only): keys 2112..2143, valid < 2116 ----
    if (w == 3) {
        const int dbase = 66 * 32;
        const int kk0 = min(dbase + key0, DD - 1);
        const int kk1 = min(dbase + key0 + 4, DD - 1);
        const __hip_bfloat16* t0 = kbase + (size_t)kk0 * CGR + quad * 8;
        const __hip_bfloat16* t1 = kbase + (size_t)kk1 * CGR + quad * 8;
        const bf16x8 Ka = ldb8(t0), Kb = ldb8(t0 + 32);
        const bf16x8 Kc = ldb8(t1), Kd = ldb8(t1 + 32);

        f32x4 SA0 = __builtin_amdgcn_mfma_f32_16x16x32_bf16(Ka, qfA0, zero, 0, 0, 0);
        SA0 = __builtin_amdgcn_mfma_f32_16x16x32_bf16(Kb, qfA1, SA0, 0, 0, 0);
        f32x4 SA1 = __builtin_amdgcn_mfma_f32_16x16x32_bf16(Kc, qfA0, zero, 0, 0, 0);
        SA1 = __builtin_amdgcn_mfma_f32_16x16x32_bf16(Kd, qfA1, SA1, 0, 0, 0);
        f32x4 SB0 = __builtin_amdgcn_mfma_f32_16x16x32_bf16(Ka, qfB0, zero, 0, 0, 0);
        SB0 = __builtin_amdgcn_mfma_f32_16x16x32_bf16(Kb, qfB1, SB0, 0, 0, 0);
        f32x4 SB1 = __builtin_amdgcn_mfma_f32_16x16x32_bf16(Kc, qfB0, zero, 0, 0, 0);
        SB1 = __builtin_amdgcn_mfma_f32_16x16x32_bf16(Kd, qfB1, SB1, 0, 0, 0);

        float eA[8], eB[8];
        #pragma unroll
        for (int r = 0; r < 4; ++r) {
            const bool v0 = (dbase + quad * 8 + r     < DD);
            const bool v1 = (dbase + quad * 8 + 4 + r < DD);
            eA[r]     = v0 ? SA0[r] : -1e30f;
            eA[4 + r] = v1 ? SA1[r] : -1e30f;
            eB[r]     = v0 ? SB0[r] : -1e30f;
            eB[4 + r] = v1 ? SB1[r] : -1e30f;
        }
        float sA = fmaxf(fmaxf(fmaxf(eA[0], eA[1]), fmaxf(eA[2], eA[3])),
                         fmaxf(fmaxf(eA[4], eA[5]), fmaxf(eA[6], eA[7])));
        sA = fmaxf(sA, __shfl_xor(sA, 16, 64));
        sA = fmaxf(sA, __shfl_xor(sA, 32, 64));
        float sB = fmaxf(fmaxf(fmaxf(eB[0], eB[1]), fmaxf(eB[2], eB[3])),
                         fmaxf(fmaxf(eB[4], eB[5]), fmaxf(eB[6], eB[7])));
        sB = fmaxf(sB, __shfl_xor(sB, 16, 64));
        sB = fmaxf(sB, __shfl_xor(sB, 32, 64));
        const float mnA = fmaxf(mA, sA), mnB = fmaxf(mB, sB);
        const float aA = ex2(mA - mnA), aB = ex2(mB - mnB);
        float lsA = 0.f, lsB = 0.f;
        #pragma unroll
        for (int jj = 0; jj < 8; ++jj) {
            eA[jj] = ex2(eA[jj] - mnA); lsA += eA[jj];
            eB[jj] = ex2(eB[jj] - mnB); lsB += eB[jj];
        }
        lA = lA * aA + lsA;
        lB = lB * aB + lsB;
        mA = mnA; mB = mnB;

        bf16x8 ptA, ptB;
        #pragma unroll
        for (int jj = 0; jj < 8; ++jj) { ptA[jj] = (__bf16)eA[jj]; ptB[jj] = (__bf16)eB[jj]; }

        int da = dbase + quad * 8;
        if (da >= DD) da = 0;                // fully-masked quads: P==0
        #pragma unroll
        for (int cf = 0; cf < 4; ++cf) {
            accA[cf] *= aA; accB[cf] *= aB;
            const bf16x8 vf = ldb8(vrow[cf] + da);
            accA[cf] = __builtin_amdgcn_mfma_f32_16x16x32_bf16(vf, ptA, accA[cf], 0, 0, 0);
            accB[cf] = __builtin_amdgcn_mfma_f32_16x16x32_bf16(vf, ptB, accB[cf], 0, 0, 0);
        }
    }

    // ---- cross-wave merge of (m, l, acc) partials via LDS ----
    if (w != 0) {
        lmS[w - 1][0][lane] = mA; lmS[w - 1][1][lane] = mB;
        llS[w - 1][0][lane] = lA; llS[w - 1][1][lane] = lB;
        #pragma unroll
        for (int cf = 0; cf < 4; ++cf) {
            *reinterpret_cast<f32x4*>(&laccS[w - 1][0][lane][cf * 4]) = accA[cf];
            *reinterpret_cast<f32x4*>(&laccS[w - 1][1][lane][cf * 4]) = accB[cf];
        }
    }
    __syncthreads();
    if (w != 0) return;

    #pragma unroll
    for (int ww = 0; ww < 3; ++ww) {
        {
            const float mo = lmS[ww][0][lane];
            const float lo = llS[ww][0][lane];
            const float mn = fmaxf(mA, mo);
            const float a0 = ex2(mA - mn);
            const float a1 = ex2(mo - mn);
            lA = lA * a0 + lo * a1;
            #pragma unroll
            for (int cf = 0; cf < 4; ++cf) {
                const f32x4 o = *reinterpret_cast<const f32x4*>(&laccS[ww][0][lane][cf * 4]);
                accA[cf] = accA[cf] * a0 + o * a1;
            }
            mA = mn;
        }
        {
            const float mo = lmS[ww][1][lane];
            const float lo = llS[ww][1][lane];
            const float mn = fmaxf(mB, mo);
            const float a0 = ex2(mB - mn);
            const float a1 = ex2(mo - mn);
            lB = lB * a0 + lo * a1;
            #pragma unroll
            for (int cf = 0; cf < 4; ++cf) {
                const f32x4 o = *reinterpret_cast<const f32x4*>(&laccS[ww][1][lane][cf * 4]);
                accB[cf] = accB[cf] * a0 + o * a1;
            }
            mB = mn;
        }
    }

    // single cross-lane reduce of the per-lane partial denominators
    lA += __shfl_xor(lA, 16, 64);
    lA += __shfl_xor(lA, 32, 64);
    lB += __shfl_xor(lB, 16, 64);
    lB += __shfl_xor(lB, 32, 64);

    const float invA = 1.f / lA;
    const float invB = 1.f / lB;
    #pragma unroll
    for (int cf = 0; cf < 4; ++cf) {
        store4bf(qrowA + cf * 16 + quad * 4, accA[cf] * invA);
        store4bf(qrowB + cf * 16 + quad * 4, accB[cf] * invB);
    }
}

// ---------------------------------------------------------------------------
// Kernel 4: fused gates via MFMA + LSTM update (round-9 form).
// grid 768 x 512.
// ---------------------------------------------------------------------------
__global__ __launch_bounds__(512) void gates_kernel(
    const __hip_bfloat16* __restrict__ xhT, const __hip_bfloat16* __restrict__ aT,
    const float* __restrict__ c_in,
    const __hip_bfloat16* __restrict__ Wr, const __hip_bfloat16* __restrict__ Wa,
    const float* __restrict__ b_i, const float* __restrict__ b_f,
    const float* __restrict__ b_g, const float* __restrict__ b_o,
    float* __restrict__ h_out)
{
    const int b = blockIdx.x;                // 0..767
    const int xcd = b & 7;
    const int j = b >> 3;                    // 0..95
    const int ng = xcd + 8 * (j / 48);
    const int yy = j % 48;
    const int n = ng >> 3, g = ng & 7;
    const int tid = threadIdx.x;
    const int w8 = tid >> 6, lane = tid & 63;
    const int gate = w8 & 3, chalf = w8 >> 2;
    const int cf0 = chalf * 2;
    const int col = lane & 15, quad = lane >> 4;

    __shared__ char smem[38400];             // max(stage 38400, exchange 24576)
    __hip_bfloat16* st = (__hip_bfloat16*)smem;
    float* ex = (float*)smem;

    const __hip_bfloat16* slab = xhT + (size_t)ng * PP * 128;

    // zero pad columns (sc = 0 and 49)
    if (tid < 96) {
        const int ck = tid / 6, r2 = tid % 6;
        const int lr = r2 >> 1, side = r2 & 1;
        const int sc = side ? 49 : 0;
        *reinterpret_cast<bf16x8*>(st + ((ck * 150) + lr * 50 + sc) * 8) =
            (bf16x8)(__bf16)0.f;
    }
    // stage 3 rows x 48 px x 16 ck, zeroing OOB rows; data at sc = px+1
    #pragma unroll
    for (int it = 0; it < 5; ++it) {
        const int u = it * 512 + tid;
        if (u < 2304) {
            const int lr = u / 768;
            const int rem = u % 768;
            const int px = rem >> 4, ck = rem & 15;
            const int ry = yy - 1 + lr;
            const int ryc = max(0, min(47, ry));
            bf16x8 vv = ldb8(slab + ((size_t)(ryc * 48 + px)) * 128 + ck * 8);
            *reinterpret_cast<bf16x8*>(st + ((ck * 150) + lr * 50 + px + 1) * 8) =
                (ry == ryc) ? vv : (bf16x8)(__bf16)0.f;
        }
    }
    __syncthreads();

    f32x4 acc[6];
    #pragma unroll
    for (int i = 0; i < 6; ++i) acc[i] = (f32x4){0.f, 0.f, 0.f, 0.f};

    const __hip_bfloat16* wgbase =
        Wr + ((size_t)(3 + gate) * 8 + g) * 36 * 2048 + col * 32 + quad * 8;

    #pragma unroll
    for (int ky = 0; ky < 3; ++ky) {
        const int lrk = ky * 50;
        #pragma unroll
        for (int kx = 0; kx < 3; ++kx) {
            const int scb = col + kx;
            #pragma unroll
            for (int c32 = 0; c32 < 4; ++c32) {
                bf16x8 bfr[3];
                #pragma unroll
                for (int nf = 0; nf < 3; ++nf)
                    bfr[nf] = *reinterpret_cast<const bf16x8*>(
                        st + (((c32 * 4 + quad) * 150) + lrk + nf * 16 + scb) * 8);
                const __hip_bfloat16* wp =
                    wgbase + ((ky * 3 + kx) * 4 + c32) * 2048;
                #pragma unroll
                for (int cc = 0; cc < 2; ++cc) {
                    const bf16x8 af = ldb8(wp + (cf0 + cc) * 512);
                    #pragma unroll
                    for (int nf = 0; nf < 3; ++nf)
                        acc[cc * 3 + nf] = __builtin_amdgcn_mfma_f32_16x16x32_bf16(
                            af, bfr[nf], acc[cc * 3 + nf], 0, 0, 0);
                }
            }
        }
    }

    {
        const __hip_bfloat16* wa =
            Wa + (size_t)gate * 32768 + ((size_t)(g * 64) + col) * 64;
        const __hip_bfloat16* ab = aT + ((size_t)ng * PP + yy * 48) * 64;
        #pragma unroll
        for (int c32 = 0; c32 < 2; ++c32) {
            bf16x8 bfr[3];
            #pragma unroll
            for (int nf = 0; nf < 3; ++nf)
                bfr[nf] = ldb8(ab + (size_t)(nf * 16 + col) * 64 + c32 * 32 + quad * 8);
            #pragma unroll
            for (int cc = 0; cc < 2; ++cc) {
                const bf16x8 af = ldb8(wa + (size_t)((cf0 + cc) * 16) * 64 + c32 * 32 + quad * 8);
                #pragma unroll
                for (int nf = 0; nf < 3; ++nf)
                    acc[cc * 3 + nf] = __builtin_amdgcn_mfma_f32_16x16x32_bf16(
                        af, bfr[nf], acc[cc * 3 + nf], 0, 0, 0);
            }
        }
    }

    const float* bias = (gate == 0) ? b_i : (gate == 1) ? b_f : (gate == 2) ? b_g : b_o;
    #pragma unroll
    for (int cc = 0; cc < 2; ++cc) {
        #pragma unroll
        for (int r = 0; r < 4; ++r) {
            const float bv = bias[g * 64 + (cf0 + cc) * 16 + quad * 4 + r];
            #pragma unroll
            for (int nf = 0; nf < 3; ++nf)
                acc[cc * 3 + nf][r] += bv;
        }
    }

    for (int hh = 0; hh < 2; ++hh) {
        __syncthreads();
        if (chalf == hh) {
            #pragma unroll
            for (int cc = 0; cc < 2; ++cc)
                #pragma unroll
                for (int nf = 0; nf < 3; ++nf)
                    #pragma unroll
                    for (int r = 0; r < 4; ++r)
                        ex[(size_t)gate * 1536 + (cc * 16 + quad * 4 + r) * 48 + nf * 16 + col] =
                            acc[cc * 3 + nf][r];
        }
        __syncthreads();
        #pragma unroll
        for (int k2 = 0; k2 < 3; ++k2) {
            const int idx = k2 * 512 + tid;
            const int co32 = idx / 48, px = idx % 48;
            const float iv = ex[0 * 1536 + co32 * 48 + px];
            const float fv = ex[1 * 1536 + co32 * 48 + px];
            const float gv = ex[2 * 1536 + co32 * 48 + px];
            const float ov = ex[3 * 1536 + co32 * 48 + px];
            const int c = g * 64 + hh * 32 + co32;
            const size_t off = ((size_t)n * CC + c) * PP + yy * 48 + px;
            const float ig = sig_fast(iv);
            const float fg = sig_fast(fv);
            const float gg = tanh_fast(gv);
            const float og = sig_fast(ov);
            const float cn = fg * c_in[off] + ig * gg;
            h_out[off] = og * tanh_fast(cn);
        }
    }
}

// ---------------------------------------------------------------------------
extern "C" void kernel_launch(void* const* d_in, const int* in_sizes, int n_in,
                              void* d_out, int out_size, void* d_ws, size_t ws_size,
                              hipStream_t stream)
{
    const float* x_in = (const float*)d_in[0];
    const float* h    = (const float*)d_in[1];
    const float* c    = (const float*)d_in[2];
    const float* tau  = (const float*)d_in[3];
    const float* W_x  = (const float*)d_in[4];
    const float* W_ig = (const float*)d_in[5];
    const float* W_q  = (const float*)d_in[6];
    const float* W_k  = (const float*)d_in[7];
    const float* W_v  = (const float*)d_in[8];
    const float* Wi_a = (const float*)d_in[9];
    const float* Wi_x = (const float*)d_in[10];
    const float* b_i  = (const float*)d_in[11];
    const float* Wf_a = (const float*)d_in[12];
    const float* Wf_x = (const float*)d_in[13];
    const float* b_f  = (const float*)d_in[14];
    const float* Wg_a = (const float*)d_in[15];
    const float* Wg_x = (const float*)d_in[16];
    const float* b_g  = (const float*)d_in[17];
    const float* Wo_a = (const float*)d_in[18];
    const float* Wo_x = (const float*)d_in[19];
    const float* b_o  = (const float*)d_in[20];
    float* out = (float*)d_out;

    // Workspace (bf16 elements), total 34,496,512 B (~32.9 MB)
    __hip_bfloat16* wsb = (__hip_bfloat16*)d_ws;
    __hip_bfloat16* xhT = wsb;                        // 4,718,592
    __hip_bfloat16* qa  = xhT + (size_t)4718592;      // 2,359,296
    __hip_bfloat16* kT  = qa  + (size_t)2359296;      // 2,166,784
    __hip_bfloat16* vv  = kT  + (size_t)2166784;      // 2,170,880
    __hip_bfloat16* Wr  = vv  + (size_t)2170880;      // 4,128,768
    __hip_bfloat16* Wa  = Wr  + (size_t)4128768;      //   131,072
    __hip_bfloat16* Wp  = Wa  + (size_t)131072;       //   393,216
    __hip_bfloat16* xiT = Wp  + (size_t)393216;       // 1,179,648

    dim3 blk(256);
    dim3 blk8(512);
    prep_kernel<<<dim3(18176), blk, 0, stream>>>(
        W_q, W_k, W_v, Wi_x, Wf_x, Wg_x, Wo_x, Wi_a, Wf_a, Wg_a, Wo_a,
        W_x, W_ig, Wr, Wa, Wp);
    xpose_kernel<<<dim3(144, NB), blk, 0, stream>>>(x_in, h, xiT, xhT);
    proj_mfma_kernel<<<dim3(192), blk, 0, stream>>>(xiT, Wp, xhT);
    conv_qkv_kernel<<<dim3(576), blk8, 0, stream>>>(xhT, Wr, tau, qa, kT, vv);
    attn_kernel<<<dim3(1152), blk, 0, stream>>>(qa, kT, vv);
    gates_kernel<<<dim3(768), blk8, 0, stream>>>(
        xhT, qa, c, Wr, Wa, b_i, b_f, b_g, b_o, out);
}

// Round 15
// 271.791 us; speedup vs baseline: 1.0881x; 1.0443x over previous
//
#include <hip/hip_runtime.h>
#include <hip/hip_bf16.h>
#include <math.h>

// Problem constants
#define NB   2
#define CIN  256
#define CC   512
#define GG   8
#define CGR  64
#define HH   48
#define WW   48
#define PP   (HH*WW)        // 2304
#define HD   46
#define WD   46
#define DD   (HD*WD)        // 2116
#define DPADV 2120          // v row stride (16B-aligned rows)
#define WRT  589824         // 512*9*128 = 8*36*2048, per-tensor reordered weight stride

typedef __bf16 bf16x8 __attribute__((ext_vector_type(8)));
typedef float  f32x4  __attribute__((ext_vector_type(4)));

__device__ __forceinline__ bf16x8 ldb8(const __hip_bfloat16* p) {
    return *reinterpret_cast<const bf16x8*>(p);
}
__device__ __forceinline__ void store4bf(__hip_bfloat16* p, f32x4 v) {
    union { __hip_bfloat16 h[4]; uint2 u; } t;
    #pragma unroll
    for (int r = 0; r < 4; ++r) t.h[r] = (__hip_bfloat16)v[r];
    *reinterpret_cast<uint2*>(p) = t.u;
}
__device__ __forceinline__ float ex2(float x) {
    return __builtin_amdgcn_exp2f(x);
}
// sigmoid(x) = 1/(1+exp(-x)); exp via exp2, fast rcp (exact at +-inf limits)
__device__ __forceinline__ float sig_fast(float x) {
    return __builtin_amdgcn_rcpf(1.f + ex2(-1.44269504088896f * x));
}
// tanh(x) = 1 - 2/(exp(2x)+1); exact at +-inf limits
__device__ __forceinline__ float tanh_fast(float x) {
    return 1.f - 2.f * __builtin_amdgcn_rcpf(ex2(2.88539008177793f * x) + 1.f);
}

// ---------------------------------------------------------------------------
// Kernel 0: weight prep (chunk-major layout).
//   Wr[t][g][chunk 36][och 64][k 32],  chunk = tap*4 + ci/32, k = ci%32
//   Wp[g][chunk 24][och 64][k 32],     chunk = ci/32 (768 ci)
// ---------------------------------------------------------------------------
__global__ __launch_bounds__(256) void prep_kernel(
    const float* __restrict__ Wq, const float* __restrict__ Wk,
    const float* __restrict__ Wv, const float* __restrict__ Wix,
    const float* __restrict__ Wfx, const float* __restrict__ Wgx,
    const float* __restrict__ Wox, const float* __restrict__ Wia,
    const float* __restrict__ Wfa, const float* __restrict__ Wga,
    const float* __restrict__ Woa, const float* __restrict__ Wx,
    const float* __restrict__ Wig,
    __hip_bfloat16* __restrict__ Wr, __hip_bfloat16* __restrict__ Wa,
    __hip_bfloat16* __restrict__ Wp)
{
    const int i = blockIdx.x * 256 + threadIdx.x;
    const int N1 = 7 * WRT;
    const int N2 = N1 + 4 * 32768;
    if (i < N1) {
        const int t = i / WRT, r = i % WRT;
        const int g = r / 73728, r2 = r % 73728;
        const int chunk = r2 / 2048, r3 = r2 % 2048;
        const int och = r3 / 32, k = r3 % 32;
        const int tap = chunk >> 2;
        const int ci = (chunk & 3) * 32 + k;
        const int co = g * 64 + och;
        const float* src;
        switch (t) {
            case 0: src = Wq;  break;  case 1: src = Wk;  break;
            case 2: src = Wv;  break;  case 3: src = Wix; break;
            case 4: src = Wfx; break;  case 5: src = Wgx; break;
            default: src = Wox;
        }
        Wr[i] = (__hip_bfloat16)src[(size_t)co * 1152 + ci * 9 + tap];
    } else if (i < N2) {
        const int j = i - N1;
        const int t = j / 32768, r = j % 32768;
        const float* src = (t == 0) ? Wia : (t == 1) ? Wfa : (t == 2) ? Wga : Woa;
        Wa[j] = (__hip_bfloat16)src[r];
    } else {
        const int j = i - N2;                // 0..393215
        const int g = j / 49152, r = j % 49152;
        const int chunk = r / 2048, r3 = r % 2048;
        const int och = r3 / 32, k = r3 % 32;
        const int c = g * 64 + och;
        const int ci = chunk * 32 + k;
        Wp[j] = (__hip_bfloat16)((ci < 256) ? Wx[(size_t)c * 256 + ci]
                                            : Wig[(size_t)c * 512 + (ci - 256)]);
    }
}

// ---------------------------------------------------------------------------
// Kernel 1a: transpose/convert (unchanged).
// ---------------------------------------------------------------------------
__global__ __launch_bounds__(256) void xpose_kernel(
    const float* __restrict__ x_in, const float* __restrict__ h,
    __hip_bfloat16* __restrict__ xiT, __hip_bfloat16* __restrict__ xhT)
{
    const int pt = blockIdx.x;
    const int n  = blockIdx.y;
    const int p0 = pt * 16;
    const int tid = threadIdx.x;

    __shared__ float xs[CIN * 17];
    __shared__ float hs[CC * 17];

    const float* xb = x_in + (size_t)n * CIN * PP;
    const float* hb = h + (size_t)n * CC * PP;
    #pragma unroll
    for (int k = 0; k < 16; ++k) {
        const int idx = k * 256 + tid;
        xs[(idx >> 4) * 17 + (idx & 15)] = xb[(size_t)(idx >> 4) * PP + p0 + (idx & 15)];
    }
    #pragma unroll
    for (int k = 0; k < 32; ++k) {
        const int idx = k * 256 + tid;
        hs[(idx >> 4) * 17 + (idx & 15)] = hb[(size_t)(idx >> 4) * PP + p0 + (idx & 15)];
    }
    __syncthreads();

    #pragma unroll
    for (int it = 0; it < 2; ++it) {
        const int u = it * 256 + tid;
        const int pix = u & 15, ck = u >> 4;
        union { __hip_bfloat16 h8[8]; bf16x8 v; } t;
        #pragma unroll
        for (int j = 0; j < 8; ++j)
            t.h8[j] = (__hip_bfloat16)xs[(ck * 8 + j) * 17 + pix];
        *reinterpret_cast<bf16x8*>(
            xiT + ((size_t)n * PP + p0 + pix) * 256 + ck * 8) = t.v;
    }
    #pragma unroll
    for (int it = 0; it < 4; ++it) {
        const int u = it * 256 + tid;
        const int pix = u & 15, ck = u >> 4;
        const int g = ck >> 3, c8 = (ck & 7) * 8;
        union { __hip_bfloat16 h8[8]; bf16x8 v; } t;
        #pragma unroll
        for (int j = 0; j < 8; ++j)
            t.h8[j] = (__hip_bfloat16)hs[(ck * 8 + j) * 17 + pix];
        *reinterpret_cast<bf16x8*>(
            xhT + ((size_t)(n * GG + g) * PP + p0 + pix) * 128 + 64 + c8) = t.v;
    }
}

// ---------------------------------------------------------------------------
// Kernel 1b: proj GEMM via MFMA. Chunk-major Wp addressing. grid 192 x 256.
// ---------------------------------------------------------------------------
__global__ __launch_bounds__(256) void proj_mfma_kernel(
    const __hip_bfloat16* __restrict__ xiT, const __hip_bfloat16* __restrict__ Wp,
    __hip_bfloat16* xhT)
{
    const int b = blockIdx.x;
    const int g = b & 7;
    const int j = b >> 3;
    const int n = j / 12;
    const int yt = j % 12;
    const int ng = n * GG + g;
    const int tid = threadIdx.x;
    const int w = tid >> 6, lane = tid & 63;
    const int col = lane & 15, quad = lane >> 4;
    const int y = yt * 4 + w;

    f32x4 acc[12];
    #pragma unroll
    for (int i = 0; i < 12; ++i) acc[i] = (f32x4){0.f, 0.f, 0.f, 0.f};

    const __hip_bfloat16* wgbase = Wp + (size_t)g * 24 * 2048 + col * 32 + quad * 8;

    for (int kk = 0; kk < 24; ++kk) {
        bf16x8 bfr[3];
        if (kk < 8) {
            const __hip_bfloat16* bp =
                xiT + ((size_t)n * PP + y * 48 + col) * 256 + kk * 32 + quad * 8;
            #pragma unroll
            for (int nf = 0; nf < 3; ++nf)
                bfr[nf] = ldb8(bp + (size_t)(nf * 16) * 256);
        } else {
            const int kh = kk - 8;
            const int gp = kh >> 1;
            const int c0 = (kh & 1) * 32;
            const __hip_bfloat16* bp =
                xhT + ((size_t)(n * GG + gp) * PP + y * 48 + col) * 128 + 64 + c0 + quad * 8;
            #pragma unroll
            for (int nf = 0; nf < 3; ++nf)
                bfr[nf] = ldb8(bp + (size_t)(nf * 16) * 128);
        }
        const __hip_bfloat16* wp = wgbase + kk * 2048;
        #pragma unroll
        for (int cf = 0; cf < 4; ++cf) {
            const bf16x8 af = ldb8(wp + cf * 512);
            #pragma unroll
            for (int nf = 0; nf < 3; ++nf)
                acc[cf * 3 + nf] = __builtin_amdgcn_mfma_f32_16x16x32_bf16(
                    af, bfr[nf], acc[cf * 3 + nf], 0, 0, 0);
        }
    }

    __hip_bfloat16* dst = xhT + (size_t)ng * PP * 128;
    #pragma unroll
    for (int cf = 0; cf < 4; ++cf)
        #pragma unroll
        for (int nf = 0; nf < 3; ++nf) {
            const int pix = y * 48 + nf * 16 + col;
            store4bf(dst + (size_t)pix * 128 + cf * 16 + quad * 4, acc[cf * 3 + nf]);
        }
}

// ---------------------------------------------------------------------------
// Kernel 2: fused q/k/v grouped 3x3 conv via MFMA (round-9 form: V output
// row-major with DPADV stride). grid 576 x 512.
// ---------------------------------------------------------------------------
__global__ __launch_bounds__(512) void conv_qkv_kernel(
    const __hip_bfloat16* __restrict__ xhT, const __hip_bfloat16* __restrict__ Wr,
    const float* __restrict__ tau,
    __hip_bfloat16* __restrict__ qT, __hip_bfloat16* __restrict__ kT,
    __hip_bfloat16* __restrict__ v)
{
    const int b = blockIdx.x;                // 0..575
    const int xcd = b & 7;
    const int j = b >> 3;
    const int s = xcd + 8 * (j / 12);
    const int yt = j % 12;
    const int t = s / 16;
    const int ng = s % 16;
    const int g = ng & 7;
    const int tid = threadIdx.x;
    const int w8 = tid >> 6, lane = tid & 63;
    const int yw = w8 & 3, chalf = w8 >> 2;
    const int cf0 = chalf * 2;
    const int col = lane & 15, quad = lane >> 4;
    const int y0 = yt * 4;
    const int yy = y0 + yw;
    const int ohw = (t == 0) ? 48 : 46;
    const int d0 = (t == 0) ? -1 : 0;
    const int soff = (t == 0) ? 1 : 0;       // stage column offset
    const bool wave_active = (yy < ohw);

    __shared__ __hip_bfloat16 st[8 * 300 * 8];   // [ck][lr*50+sc] x 8 bf16

    const __hip_bfloat16* slab = xhT + (size_t)ng * PP * 128;
    const __hip_bfloat16* wgbase =
        Wr + ((size_t)t * 8 + g) * 36 * 2048 + col * 32 + quad * 8;

    // zero the pad columns once (never overwritten by data stages)
    if (tid < 96) {
        const int ck = tid / 12, r2 = tid % 12;
        const int lr = r2 >> 1, side = r2 & 1;
        const int sc = side ? 49 : (soff ? 0 : 48);
        *reinterpret_cast<bf16x8*>(st + ((ck * 300) + lr * 50 + sc) * 8) =
            (bf16x8)(__bf16)0.f;
    }

    f32x4 acc[6];
    #pragma unroll
    for (int i = 0; i < 6; ++i) acc[i] = (f32x4){0.f, 0.f, 0.f, 0.f};

    for (int hc = 0; hc < 2; ++hc) {
        __syncthreads();
        #pragma unroll
        for (int it = 0; it < 5; ++it) {
            const int u = it * 512 + tid;
            if (u < 2304) {
                const int lr = u / 384;
                const int rem = u % 384;
                const int px = rem >> 3, ck = rem & 7;
                const int ry = y0 + d0 + lr;
                const int ryc = max(0, min(47, ry));
                bf16x8 vv = ldb8(slab + ((size_t)(ryc * 48 + px)) * 128 + hc * 64 + ck * 8);
                *reinterpret_cast<bf16x8*>(st + ((ck * 300) + lr * 50 + px + soff) * 8) =
                    (ry == ryc) ? vv : (bf16x8)(__bf16)0.f;
            }
        }
        __syncthreads();
        if (!wave_active) continue;

        #pragma unroll
        for (int ky = 0; ky < 3; ++ky) {
            const int lrk = (yw + ky) * 50;
            #pragma unroll
            for (int kx = 0; kx < 3; ++kx) {
                const int scb = col + kx;
                #pragma unroll
                for (int c32 = 0; c32 < 2; ++c32) {
                    bf16x8 bfr[3];
                    #pragma unroll
                    for (int nf = 0; nf < 3; ++nf)
                        bfr[nf] = *reinterpret_cast<const bf16x8*>(
                            st + (((c32 * 4 + quad) * 300) + lrk + nf * 16 + scb) * 8);
                    const __hip_bfloat16* wp =
                        wgbase + ((ky * 3 + kx) * 4 + hc * 2 + c32) * 2048;
                    if (t != 2) {
                        #pragma unroll
                        for (int cc = 0; cc < 2; ++cc) {
                            const bf16x8 af = ldb8(wp + (cf0 + cc) * 512);
                            #pragma unroll
                            for (int nf = 0; nf < 3; ++nf)
                                acc[cc * 3 + nf] = __builtin_amdgcn_mfma_f32_16x16x32_bf16(
                                    af, bfr[nf], acc[cc * 3 + nf], 0, 0, 0);
                        }
                    } else {
                        #pragma unroll
                        for (int cc = 0; cc < 2; ++cc) {
                            const bf16x8 af = ldb8(wp + (cf0 + cc) * 512);
                            #pragma unroll
                            for (int nf = 0; nf < 3; ++nf)
                                acc[cc * 3 + nf] = __builtin_amdgcn_mfma_f32_16x16x32_bf16(
                                    bfr[nf], af, acc[cc * 3 + nf], 0, 0, 0);
                        }
                    }
                }
            }
        }
    }

    if (!wave_active) return;
    if (t == 0) {
        const float ts = tau[g] * 1.44269504088896340736f;  // fold log2(e)
        __hip_bfloat16* dst = qT + (size_t)ng * PP * 64;
        #pragma unroll
        for (int cc = 0; cc < 2; ++cc)
            #pragma unroll
            for (int nf = 0; nf < 3; ++nf) {
                const int pix = yy * 48 + nf * 16 + col;
                store4bf(dst + (size_t)pix * 64 + (cf0 + cc) * 16 + quad * 4,
                         acc[cc * 3 + nf] * ts);
            }
    } else if (t == 1) {
        __hip_bfloat16* dst = kT + (size_t)ng * DD * 64;
        #pragma unroll
        for (int cc = 0; cc < 2; ++cc)
            #pragma unroll
            for (int nf = 0; nf < 3; ++nf) {
                const int x = nf * 16 + col;
                if (x < 46) {
                    const int pix = yy * 46 + x;
                    store4bf(dst + (size_t)pix * 64 + (cf0 + cc) * 16 + quad * 4,
                             acc[cc * 3 + nf]);
                }
            }
    } else {
        __hip_bfloat16* dst = v + (size_t)ng * 64 * DPADV;
        #pragma unroll
        for (int cc = 0; cc < 2; ++cc) {
            const int co = (cf0 + cc) * 16 + col;
            #pragma unroll
            for (int nf = 0; nf < 3; ++nf) {
                const int x4 = nf * 16 + quad * 4;
                #pragma unroll
                for (int r = 0; r < 4; ++r) {
                    if (x4 + r < 46)
                        dst[(size_t)co * DPADV + yy * 46 + x4 + r] =
                            (__hip_bfloat16)acc[cc * 3 + nf][r];
                }
            }
        }
    }
}

// ---------------------------------------------------------------------------
// Kernel 3: MFMA flash attention, 4 Q-TILES PER WAVE (64 q rows/block).
// attn is K/V TRAFFIC-bound (R10: traffic x2 -> time +60%; occupancy/
// prefetch/layout all null). 4 tiles share each K/V fragment -> K/V bytes
// per dispatch halve vs the 2-tile form. Per-tile-sequential softmax keeps
// S transient (VGPR bounded). Two-stage LDS merge (w1,w3 -> w0,w2; then
// w2 -> w0), rows padded to 20 floats for 16B alignment. grid 576 x 256.
// ---------------------------------------------------------------------------
__global__ __launch_bounds__(256) void attn_kernel(
    __hip_bfloat16* qa,                      // qT in (tau*log2e-scaled), aT out
    const __hip_bfloat16* __restrict__ kT,
    const __hip_bfloat16* __restrict__ vT)
{
    const int idx = blockIdx.x;              // 0..575, idx&7 = group (XCD affinity)
    const int j3  = idx >> 3;                // 0..71
    const int sub = (j3 >= 36) ? 1 : 0;
    const int ng  = (idx & 7) + 8 * sub;
    const int qt  = j3 - 36 * sub;           // 0..35
    const int tid = threadIdx.x;
    const int w = tid >> 6, lane = tid & 63;
    const int col = lane & 15, quad = lane >> 4;
    const int qbase = qt * 64;

    // per-wave key-chunk: [it0, it1) full 32-key tiles; w==3 also does tail
    const int it0 = w * 17;
    const int it1 = (w < 3) ? (it0 + 17) : 66;

    __shared__ float mg[2][4][64][20];       // [buf][tile][lane][acc16,m,l,pad2] = 40KB

    __hip_bfloat16* qrow[4];
    bf16x8 qf0[4], qf1[4];
    #pragma unroll
    for (int t = 0; t < 4; ++t) {
        qrow[t] = qa + ((size_t)ng * PP + qbase + t * 16 + col) * CGR;
        qf0[t] = ldb8(qrow[t] + quad * 8);
        qf1[t] = ldb8(qrow[t] + 32 + quad * 8);
    }

    const __hip_bfloat16* kbase = kT + (size_t)ng * DD * CGR;
    const __hip_bfloat16* vbase = vT + (size_t)ng * CGR * DPADV;
    const __hip_bfloat16* vrow[4];
    #pragma unroll
    for (int cf = 0; cf < 4; ++cf)
        vrow[cf] = vbase + (size_t)(cf * 16 + col) * DPADV;

    // permuted tile-local key for this lane's A-rows
    const int key0 = ((col >> 2) << 3) + (col & 3);
    const __hip_bfloat16* p0 = kbase + (size_t)(it0 * 32 + key0) * CGR + quad * 8;
    const __hip_bfloat16* p1 = p0 + 4 * CGR;

    f32x4 acc[4][4];                         // [tile][cf]
    #pragma unroll
    for (int t = 0; t < 4; ++t)
        #pragma unroll
        for (int cf = 0; cf < 4; ++cf)
            acc[t][cf] = (f32x4){0.f, 0.f, 0.f, 0.f};
    float m[4] = {-INFINITY, -INFINITY, -INFINITY, -INFINITY};
    float l[4] = {0.f, 0.f, 0.f, 0.f};       // PER-LANE partial denominators
    const f32x4 zero = {0.f, 0.f, 0.f, 0.f};

    for (int it = it0; it < it1; ++it) {
        const int dbase = it * 32;
        const bf16x8 K0a = ldb8(p0), K0b = ldb8(p0 + 32);
        const bf16x8 K1a = ldb8(p1), K1b = ldb8(p1 + 32);
        p0 += 32 * CGR; p1 += 32 * CGR;

        // V loads shared by all 4 tiles; latency hides under softmax chains
        const int da = dbase + quad * 8;
        const bf16x8 vf0 = ldb8(vrow[0] + da);
        const bf16x8 vf1 = ldb8(vrow[1] + da);
        const bf16x8 vf2 = ldb8(vrow[2] + da);
        const bf16x8 vf3 = ldb8(vrow[3] + da);

        #pragma unroll
        for (int t = 0; t < 4; ++t) {
            f32x4 S0 = __builtin_amdgcn_mfma_f32_16x16x32_bf16(K0a, qf0[t], zero, 0, 0, 0);
            S0 = __builtin_amdgcn_mfma_f32_16x16x32_bf16(K0b, qf1[t], S0, 0, 0, 0);
            f32x4 S1 = __builtin_amdgcn_mfma_f32_16x16x32_bf16(K1a, qf0[t], zero, 0, 0, 0);
            S1 = __builtin_amdgcn_mfma_f32_16x16x32_bf16(K1b, qf1[t], S1, 0, 0, 0);

            const float lmx = fmaxf(fmaxf(fmaxf(S0[0], S0[1]), fmaxf(S0[2], S0[3])),
                                    fmaxf(fmaxf(S1[0], S1[1]), fmaxf(S1[2], S1[3])));
            if (__any(lmx > m[t] + 8.f)) {
                float s = lmx;
                s = fmaxf(s, __shfl_xor(s, 16, 64));
                s = fmaxf(s, __shfl_xor(s, 32, 64));
                const float mn = fmaxf(m[t], s);
                const float a = ex2(m[t] - mn);
                l[t] *= a;
                #pragma unroll
                for (int cf = 0; cf < 4; ++cf) acc[t][cf] *= a;
                m[t] = mn;
            }

            float e[8];
            float lsum = 0.f;
            #pragma unroll
            for (int r = 0; r < 4; ++r) {
                e[r]     = ex2(S0[r] - m[t]);
                e[4 + r] = ex2(S1[r] - m[t]);
                lsum += e[r] + e[4 + r];
            }
            l[t] += lsum;

            bf16x8 pt;
            #pragma unroll
            for (int jj = 0; jj < 8; ++jj) pt[jj] = (__bf16)e[jj];

            acc[t][0] = __builtin_amdgcn_mfma_f32_16x16x32_bf16(vf0, pt, acc[t][0], 0, 0, 0);
            acc[t][1] = __builtin_amdgcn_mfma_f32_16x16x32_bf16(vf1, pt, acc[t][1], 0, 0, 0);
            acc[t][2] = __builtin_amdgcn_mfma_f32_16x16x32_bf16(vf2, pt, acc[t][2], 0, 0, 0);
            acc[t][3] = __builtin_amdgcn_mfma_f32_16x16x32_bf16(vf3, pt, acc[t][3], 0, 0, 0);
        }
    }

    // ---- masked tail tile (w==3 only): keys 2112..2143, valid < 2116 ----
    if (w == 3) {
        const int dbase = 66 * 32;
        const int kk0 = min(dbase + key0, DD - 1);
        const int kk1 = min(dbase + key0 + 4, DD - 1);
        const __hip_bfloat16* t0p = kbase + (size_t)kk0 * CGR + quad * 8;
        const __hip_bfloat16* t1p = kbase + (size_t)kk1 * CGR + quad * 8;
        const bf16x8 Ka = ldb8(t0p), Kb = ldb8(t0p + 32);
        const bf16x8 Kc = ldb8(t1p), Kd = ldb8(t1p + 32);

        int da = dbase + quad * 8;
        if (da >= DD) da = 0;                // fully-masked quads: P==0
        const bf16x8 tv0 = ldb8(vrow[0] + da);
        const bf16x8 tv1 = ldb8(vrow[1] + da);
        const bf16x8 tv2 = ldb8(vrow[2] + da);
        const bf16x8 tv3 = ldb8(vrow[3] + da);

        #pragma unroll
        for (int t = 0; t < 4; ++t) {
            f32x4 S0 = __builtin_amdgcn_mfma_f32_16x16x32_bf16(Ka, qf0[t], zero, 0, 0, 0);
            S0 = __builtin_amdgcn_mfma_f32_16x16x32_bf16(Kb, qf1[t], S0, 0, 0, 0);
            f32x4 S1 = __builtin_amdgcn_mfma_f32_16x16x32_bf16(Kc, qf0[t], zero, 0, 0, 0);
            S1 = __builtin_amdgcn_mfma_f32_16x16x32_bf16(Kd, qf1[t], S1, 0, 0, 0);

            float e[8];
            #pragma unroll
            for (int r = 0; r < 4; ++r) {
                e[r]     = (dbase + quad * 8 + r     < DD) ? S0[r] : -1e30f;
                e[4 + r] = (dbase + quad * 8 + 4 + r < DD) ? S1[r] : -1e30f;
            }
            float s = fmaxf(fmaxf(fmaxf(e[0], e[1]), fmaxf(e[2], e[3])),
                            fmaxf(fmaxf(e[4], e[5]), fmaxf(e[6], e[7])));
            s = fmaxf(s, __shfl_xor(s, 16, 64));
            s = fmaxf(s, __shfl_xor(s, 32, 64));
            const float mn = fmaxf(m[t], s);
            const float a = ex2(m[t] - mn);
            float lsum = 0.f;
            #pragma unroll
            for (int jj = 0; jj < 8; ++jj) { e[jj] = ex2(e[jj] - mn); lsum += e[jj]; }
            l[t] = l[t] * a + lsum;
            m[t] = mn;

            bf16x8 pt;
            #pragma unroll
            for (int jj = 0; jj < 8; ++jj) pt[jj] = (__bf16)e[jj];

            #pragma unroll
            for (int cf = 0; cf < 4; ++cf) acc[t][cf] *= a;
            acc[t][0] = __builtin_amdgcn_mfma_f32_16x16x32_bf16(tv0, pt, acc[t][0], 0, 0, 0);
            acc[t][1] = __builtin_amdgcn_mfma_f32_16x16x32_bf16(tv1, pt, acc[t][1], 0, 0, 0);
            acc[t][2] = __builtin_amdgcn_mfma_f32_16x16x32_bf16(tv2, pt, acc[t][2], 0, 0, 0);
            acc[t][3] = __builtin_amdgcn_mfma_f32_16x16x32_bf16(tv3, pt, acc[t][3], 0, 0, 0);
        }
    }

    // ---- two-stage cross-wave merge via LDS ----
    // stage 1: w1 -> buf0, w3 -> buf1
    if (w == 1 || w == 3) {
        const int bs = (w == 3) ? 1 : 0;
        #pragma unroll
        for (int t = 0; t < 4; ++t) {
            #pragma unroll
            for (int cf = 0; cf < 4; ++cf)
                *reinterpret_cast<f32x4*>(&mg[bs][t][lane][cf * 4]) = acc[t][cf];
            mg[bs][t][lane][16] = m[t];
            mg[bs][t][lane][17] = l[t];
        }
    }
    __syncthreads();
    if (w == 0 || w == 2) {
        const int bs = (w == 2) ? 1 : 0;
        #pragma unroll
        for (int t = 0; t < 4; ++t) {
            const float mo = mg[bs][t][lane][16];
            const float lo = mg[bs][t][lane][17];
            const float mn = fmaxf(m[t], mo);
            const float a0 = ex2(m[t] - mn);
            const float a1 = ex2(mo - mn);
            l[t] = l[t] * a0 + lo * a1;
            #pragma unroll
            for (int cf = 0; cf < 4; ++cf) {
                const f32x4 o = *reinterpret_cast<const f32x4*>(&mg[bs][t][lane][cf * 4]);
                acc[t][cf] = acc[t][cf] * a0 + o * a1;
            }
            m[t] = mn;
        }
    }
    __syncthreads();
    // stage 2: w2 -> buf0
    if (w == 2) {
        #pragma unroll
        for (int t = 0; t < 4; ++t) {
            #pragma unroll
            for (int cf = 0; cf < 4; ++cf)
                *reinterpret_cast<f32x4*>(&mg[0][t][lane][cf * 4]) = acc[t][cf];
            mg[0][t][lane][16] = m[t];
            mg[0][t][lane][17] = l[t];
        }
    }
    __syncthreads();
    if (w != 0) return;

    #pragma unroll
    for (int t = 0; t < 4; ++t) {
        const float mo = mg[0][t][lane][16];
        const float lo = mg[0][t][lane][17];
        const float mn = fmaxf(m[t], mo);
        const float a0 = ex2(m[t] - mn);
        const float a1 = ex2(mo - mn);
        l[t] = l[t] * a0 + lo * a1;
        #pragma unroll
        for (int cf = 0; cf < 4; ++cf) {
            const f32x4 o = *reinterpret_cast<const f32x4*>(&mg[0][t][lane][cf * 4]);
            acc[t][cf] = acc[t][cf] * a0 + o * a1;
        }
        m[t] = mn;
    }

    // single cross-lane reduce of the per-lane partial denominators
    #pragma unroll
    for (int t = 0; t < 4; ++t) {
        l[t] += __shfl_xor(l[t], 16, 64);
        l[t] += __shfl_xor(l[t], 32, 64);
        const float inv = 1.f / l[t];
        #pragma unroll
        for (int cf = 0; cf < 4; ++cf)
            store4bf(qrow[t] + cf * 16 + quad * 4, acc[t][cf] * inv);
    }
}

// ---------------------------------------------------------------------------
// Kernel 4: fused gates via MFMA + LSTM update (round-9 form).
// grid 768 x 512.
// ---------------------------------------------------------------------------
__global__ __launch_bounds__(512) void gates_kernel(
    const __hip_bfloat16* __restrict__ xhT, const __hip_bfloat16* __restrict__ aT,
    const float* __restrict__ c_in,
    const __hip_bfloat16* __restrict__ Wr, const __hip_bfloat16* __restrict__ Wa,
    const float* __restrict__ b_i, const float* __restrict__ b_f,
    const float* __restrict__ b_g, const float* __restrict__ b_o,
    float* __restrict__ h_out)
{
    const int b = blockIdx.x;                // 0..767
    const int xcd = b & 7;
    const int j = b >> 3;                    // 0..95
    const int ng = xcd + 8 * (j / 48);
    const int yy = j % 48;
    const int n = ng >> 3, g = ng & 7;
    const int tid = threadIdx.x;
    const int w8 = tid >> 6, lane = tid & 63;
    const int gate = w8 & 3, chalf = w8 >> 2;
    const int cf0 = chalf * 2;
    const int col = lane & 15, quad = lane >> 4;

    __shared__ char smem[38400];             // max(stage 38400, exchange 24576)
    __hip_bfloat16* st = (__hip_bfloat16*)smem;
    float* ex = (float*)smem;

    const __hip_bfloat16* slab = xhT + (size_t)ng * PP * 128;

    // zero pad columns (sc = 0 and 49)
    if (tid < 96) {
        const int ck = tid / 6, r2 = tid % 6;
        const int lr = r2 >> 1, side = r2 & 1;
        const int sc = side ? 49 : 0;
        *reinterpret_cast<bf16x8*>(st + ((ck * 150) + lr * 50 + sc) * 8) =
            (bf16x8)(__bf16)0.f;
    }
    // stage 3 rows x 48 px x 16 ck, zeroing OOB rows; data at sc = px+1
    #pragma unroll
    for (int it = 0; it < 5; ++it) {
        const int u = it * 512 + tid;
        if (u < 2304) {
            const int lr = u / 768;
            const int rem = u % 768;
            const int px = rem >> 4, ck = rem & 15;
            const int ry = yy - 1 + lr;
            const int ryc = max(0, min(47, ry));
            bf16x8 vv = ldb8(slab + ((size_t)(ryc * 48 + px)) * 128 + ck * 8);
            *reinterpret_cast<bf16x8*>(st + ((ck * 150) + lr * 50 + px + 1) * 8) =
                (ry == ryc) ? vv : (bf16x8)(__bf16)0.f;
        }
    }
    __syncthreads();

    f32x4 acc[6];
    #pragma unroll
    for (int i = 0; i < 6; ++i) acc[i] = (f32x4){0.f, 0.f, 0.f, 0.f};

    const __hip_bfloat16* wgbase =
        Wr + ((size_t)(3 + gate) * 8 + g) * 36 * 2048 + col * 32 + quad * 8;

    #pragma unroll
    for (int ky = 0; ky < 3; ++ky) {
        const int lrk = ky * 50;
        #pragma unroll
        for (int kx = 0; kx < 3; ++kx) {
            const int scb = col + kx;
            #pragma unroll
            for (int c32 = 0; c32 < 4; ++c32) {
                bf16x8 bfr[3];
                #pragma unroll
                for (int nf = 0; nf < 3; ++nf)
                    bfr[nf] = *reinterpret_cast<const bf16x8*>(
                        st + (((c32 * 4 + quad) * 150) + lrk + nf * 16 + scb) * 8);
                const __hip_bfloat16* wp =
                    wgbase + ((ky * 3 + kx) * 4 + c32) * 2048;
                #pragma unroll
                for (int cc = 0; cc < 2; ++cc) {
                    const bf16x8 af = ldb8(wp + (cf0 + cc) * 512);
                    #pragma unroll
                    for (int nf = 0; nf < 3; ++nf)
                        acc[cc * 3 + nf] = __builtin_amdgcn_mfma_f32_16x16x32_bf16(
                            af, bfr[nf], acc[cc * 3 + nf], 0, 0, 0);
                }
            }
        }
    }

    {
        const __hip_bfloat16* wa =
            Wa + (size_t)gate * 32768 + ((size_t)(g * 64) + col) * 64;
        const __hip_bfloat16* ab = aT + ((size_t)ng * PP + yy * 48) * 64;
        #pragma unroll
        for (int c32 = 0; c32 < 2; ++c32) {
            bf16x8 bfr[3];
            #pragma unroll
            for (int nf = 0; nf < 3; ++nf)
                bfr[nf] = ldb8(ab + (size_t)(nf * 16 + col) * 64 + c32 * 32 + quad * 8);
            #pragma unroll
            for (int cc = 0; cc < 2; ++cc) {
                const bf16x8 af = ldb8(wa + (size_t)((cf0 + cc) * 16) * 64 + c32 * 32 + quad * 8);
                #pragma unroll
                for (int nf = 0; nf < 3; ++nf)
                    acc[cc * 3 + nf] = __builtin_amdgcn_mfma_f32_16x16x32_bf16(
                        af, bfr[nf], acc[cc * 3 + nf], 0, 0, 0);
            }
        }
    }

    const float* bias = (gate == 0) ? b_i : (gate == 1) ? b_f : (gate == 2) ? b_g : b_o;
    #pragma unroll
    for (int cc = 0; cc < 2; ++cc) {
        #pragma unroll
        for (int r = 0; r < 4; ++r) {
            const float bv = bias[g * 64 + (cf0 + cc) * 16 + quad * 4 + r];
            #pragma unroll
            for (int nf = 0; nf < 3; ++nf)
                acc[cc * 3 + nf][r] += bv;
        }
    }

    for (int hh = 0; hh < 2; ++hh) {
        __syncthreads();
        if (chalf == hh) {
            #pragma unroll
            for (int cc = 0; cc < 2; ++cc)
                #pragma unroll
                for (int nf = 0; nf < 3; ++nf)
                    #pragma unroll
                    for (int r = 0; r < 4; ++r)
                        ex[(size_t)gate * 1536 + (cc * 16 + quad * 4 + r) * 48 + nf * 16 + col] =
                            acc[cc * 3 + nf][r];
        }
        __syncthreads();
        #pragma unroll
        for (int k2 = 0; k2 < 3; ++k2) {
            const int idx = k2 * 512 + tid;
            const int co32 = idx / 48, px = idx % 48;
            const float iv = ex[0 * 1536 + co32 * 48 + px];
            const float fv = ex[1 * 1536 + co32 * 48 + px];
            const float gv = ex[2 * 1536 + co32 * 48 + px];
            const float ov = ex[3 * 1536 + co32 * 48 + px];
            const int c = g * 64 + hh * 32 + co32;
            const size_t off = ((size_t)n * CC + c) * PP + yy * 48 + px;
            const float ig = sig_fast(iv);
            const float fg = sig_fast(fv);
            const float gg = tanh_fast(gv);
            const float og = sig_fast(ov);
            const float cn = fg * c_in[off] + ig * gg;
            h_out[off] = og * tanh_fast(cn);
        }
    }
}

// ---------------------------------------------------------------------------
extern "C" void kernel_launch(void* const* d_in, const int* in_sizes, int n_in,
                              void* d_out, int out_size, void* d_ws, size_t ws_size,
                              hipStream_t stream)
{
    const float* x_in = (const float*)d_in[0];
    const float* h    = (const float*)d_in[1];
    const float* c    = (const float*)d_in[2];
    const float* tau  = (const float*)d_in[3];
    const float* W_x  = (const float*)d_in[4];
    const float* W_ig = (const float*)d_in[5];
    const float* W_q  = (const float*)d_in[6];
    const float* W_k  = (const float*)d_in[7];
    const float* W_v  = (const float*)d_in[8];
    const float* Wi_a = (const float*)d_in[9];
    const float* Wi_x = (const float*)d_in[10];
    const float* b_i  = (const float*)d_in[11];
    const float* Wf_a = (const float*)d_in[12];
    const float* Wf_x = (const float*)d_in[13];
    const float* b_f  = (const float*)d_in[14];
    const float* Wg_a = (const float*)d_in[15];
    const float* Wg_x = (const float*)d_in[16];
    const float* b_g  = (const float*)d_in[17];
    const float* Wo_a = (const float*)d_in[18];
    const float* Wo_x = (const float*)d_in[19];
    const float* b_o  = (const float*)d_in[20];
    float* out = (float*)d_out;

    // Workspace (bf16 elements), total 34,496,512 B (~32.9 MB)
    __hip_bfloat16* wsb = (__hip_bfloat16*)d_ws;
    __hip_bfloat16* xhT = wsb;                        // 4,718,592
    __hip_bfloat16* qa  = xhT + (size_t)4718592;      // 2,359,296
    __hip_bfloat16* kT  = qa  + (size_t)2359296;      // 2,166,784
    __hip_bfloat16* vv  = kT  + (size_t)2166784;      // 2,170,880
    __hip_bfloat16* Wr  = vv  + (size_t)2170880;      // 4,128,768
    __hip_bfloat16* Wa  = Wr  + (size_t)4128768;      //   131,072
    __hip_bfloat16* Wp  = Wa  + (size_t)131072;       //   393,216
    __hip_bfloat16* xiT = Wp  + (size_t)393216;       // 1,179,648

    dim3 blk(256);
    dim3 blk8(512);
    prep_kernel<<<dim3(18176), blk, 0, stream>>>(
        W_q, W_k, W_v, Wi_x, Wf_x, Wg_x, Wo_x, Wi_a, Wf_a, Wg_a, Wo_a,
        W_x, W_ig, Wr, Wa, Wp);
    xpose_kernel<<<dim3(144, NB), blk, 0, stream>>>(x_in, h, xiT, xhT);
    proj_mfma_kernel<<<dim3(192), blk, 0, stream>>>(xiT, Wp, xhT);
    conv_qkv_kernel<<<dim3(576), blk8, 0, stream>>>(xhT, Wr, tau, qa, kT, vv);
    attn_kernel<<<dim3(576), blk, 0, stream>>>(qa, kT, vv);
    gates_kernel<<<dim3(768), blk8, 0, stream>>>(
        xhT, qa, c, Wr, Wa, b_i, b_f, b_g, b_o, out);
}